// Round 3
// baseline (239.062 us; speedup 1.0000x reference)
//
#include <hip/hip_runtime.h>
#include <hip/hip_bf16.h>
#include <stdint.h>

#define S_LEN   2048
#define D_MODEL 1024
#define NH      16
#define DH      64
#define BATCH   2
#define TOKENS  (BATCH * S_LEN)   // 4096

typedef __bf16 bf16;
typedef __bf16 bf16x8 __attribute__((ext_vector_type(8)));
typedef __bf16 b16x4  __attribute__((ext_vector_type(4)));
typedef float  f32x4  __attribute__((ext_vector_type(4)));
typedef float  f32x16 __attribute__((ext_vector_type(16)));
typedef unsigned int uint32;

__device__ __forceinline__ void async_lds16(const void* g, void* l) {
  __builtin_amdgcn_global_load_lds((__attribute__((address_space(1))) void*)g,
                                   (__attribute__((address_space(3))) void*)l,
                                   16, 0, 0);
}

// ---------------------------------------------------------------------------
// fp32 -> bf16 bulk convert (8 elems/thread)
// ---------------------------------------------------------------------------
__global__ __launch_bounds__(256) void convert_kernel(
    const float* __restrict__ src, bf16* __restrict__ dst, int n8) {
  const int i = blockIdx.x * 256 + threadIdx.x;
  if (i >= n8) return;
  const f32x4 a = *(const f32x4*)(src + (size_t)i * 8);
  const f32x4 b = *(const f32x4*)(src + (size_t)i * 8 + 4);
  bf16x8 o;
#pragma unroll
  for (int j = 0; j < 4; j++) { o[j] = (bf16)a[j]; o[j + 4] = (bf16)b[j]; }
  *(bf16x8*)(dst + (size_t)i * 8) = o;
}

// ---------------------------------------------------------------------------
// GEMM core (m97-style): C = A * B^T, bf16, async global->LDS, 128x128, BK=32.
// ---------------------------------------------------------------------------
#define BM 128
#define BN 128
#define BK 32

#define GEMM_CORE(APTR, BPTR, KDIM)                                              \
  __shared__ __align__(16) bf16 As[BM * BK];                                     \
  __shared__ __align__(16) bf16 Bs[BN * BK];                                     \
  const int tid  = threadIdx.x;                                                  \
  const int wave = tid >> 6, lane = tid & 63;                                    \
  const int quad = lane >> 4, l16 = lane & 15;                                   \
  const int m0 = blockIdx.y * BM;                                                \
  const int n0 = blockIdx.x * BN;                                                \
  const int wm = (wave >> 1) * 64, wn = (wave & 1) * 64;                         \
  f32x4 acc[4][4] = {};                                                          \
  const int c0 = tid, c1 = tid + 256;                                            \
  for (int k0 = 0; k0 < (KDIM); k0 += BK) {                                      \
    async_lds16((APTR) + (size_t)(m0 + (c0 >> 2)) * (KDIM) + k0 + (c0 & 3) * 8,  \
                As + c0 * 8);                                                    \
    async_lds16((APTR) + (size_t)(m0 + (c1 >> 2)) * (KDIM) + k0 + (c1 & 3) * 8,  \
                As + c1 * 8);                                                    \
    async_lds16((BPTR) + (size_t)(n0 + (c0 >> 2)) * (KDIM) + k0 + (c0 & 3) * 8,  \
                Bs + c0 * 8);                                                    \
    async_lds16((BPTR) + (size_t)(n0 + (c1 >> 2)) * (KDIM) + k0 + (c1 & 3) * 8,  \
                Bs + c1 * 8);                                                    \
    __syncthreads();                                                             \
    bf16x8 af[4], bfr[4];                                                        \
    _Pragma("unroll") for (int i = 0; i < 4; i++)                                \
        af[i] = *(const bf16x8*)(As + (wm + i * 16 + l16) * BK + quad * 8);      \
    _Pragma("unroll") for (int j = 0; j < 4; j++)                                \
        bfr[j] = *(const bf16x8*)(Bs + (wn + j * 16 + l16) * BK + quad * 8);     \
    _Pragma("unroll") for (int i = 0; i < 4; i++)                                \
      _Pragma("unroll") for (int j = 0; j < 4; j++)                              \
        acc[i][j] = __builtin_amdgcn_mfma_f32_16x16x32_bf16(af[i], bfr[j],       \
                                                            acc[i][j], 0, 0, 0); \
    __syncthreads();                                                             \
  }

// GEMM 1: qkv = xb @ Wqkvb^T -> Q (b,h,s,d, x1/8), K (b,h,s,d), VT (b,h,d,s).
__global__ __launch_bounds__(256) void gemm_qkv_kernel(
    const bf16* __restrict__ X, const bf16* __restrict__ W,
    bf16* __restrict__ Qo, bf16* __restrict__ Ko, bf16* __restrict__ VTo) {
  GEMM_CORE(X, W, D_MODEL)
  const int t = n0 >> 10;  // 0=q 1=k 2=v (uniform per block)
#pragma unroll
  for (int i = 0; i < 4; i++) {
    const int rowb = m0 + wm + i * 16 + quad * 4;   // multiple of 4
    const int b = rowb >> 11, s0 = rowb & 2047;
#pragma unroll
    for (int j = 0; j < 4; j++) {
      const int col = n0 + wn + j * 16 + l16;
      const int h = (col >> 6) & 15, d = col & 63;
      if (t == 2) {
        b16x4 v4;
#pragma unroll
        for (int r = 0; r < 4; r++) v4[r] = (bf16)acc[i][j][r];
        *(b16x4*)(VTo + ((size_t)(b * NH + h) * DH + d) * S_LEN + s0) = v4;
      } else {
#pragma unroll
        for (int r = 0; r < 4; r++) {
          const float v = acc[i][j][r];
          if (t == 0)
            Qo[((size_t)(b * NH + h) * S_LEN + s0 + r) * DH + d] = (bf16)(v * 0.125f);
          else
            Ko[((size_t)(b * NH + h) * S_LEN + s0 + r) * DH + d] = (bf16)v;
        }
      }
    }
  }
}

// GEMM 2: out = AO @ Woutb^T -> d_out fp32
__global__ __launch_bounds__(256) void gemm_out_kernel(
    const bf16* __restrict__ A, const bf16* __restrict__ W,
    float* __restrict__ Out) {
  GEMM_CORE(A, W, D_MODEL)
#pragma unroll
  for (int i = 0; i < 4; i++) {
    const int rowb = m0 + wm + i * 16 + quad * 4;
#pragma unroll
    for (int j = 0; j < 4; j++) {
      const int col = n0 + wn + j * 16 + l16;
#pragma unroll
      for (int r = 0; r < 4; r++)
        Out[(size_t)(rowb + r) * D_MODEL + col] = acc[i][j][r];
    }
  }
}

// ---------------------------------------------------------------------------
// Flash attention v8: NO LDS staging, NO main-loop barriers.
// K/V per head (512 KB) is L2-resident (XCD remap -> 2 MB/XCD working set);
// each wave reads its MFMA fragments directly from global (L2 hits), so the
// 8 waves run free and MFMA/VALU phases of different waves overlap (m114)
// instead of being barrier-serialized (round-2 post-mortem: 32% stall).
// K frags register-double-buffered (prefetch t+1 before QK of t); V frags
// single-buffered, issued at body top ~1200 cyc before PV use. The in-order
// VMEM queue gives counted-vmcnt waits for free.
// 64 q-rows/wave; 8 waves = 2 kv-groups x 4 q-waves; 256 blocks (1/CU).
// LDS only for the final kv-split merge (33 KB).
// Layouts (mfma_f32_32x32x16_bf16, m74/m101-verified C map):
//   C: col=lane&31, row=(r&3)+8*(r>>2)+4*(lane>>5)
//   A: row=lane&31, k=hi*8+j     B: col=lane&31, k=hi*8+j
// ---------------------------------------------------------------------------
__device__ __forceinline__ void attn_body(
    const bf16* __restrict__ klane, const bf16* __restrict__ vlane, int t,
    const bf16x8 (&KU)[8], bf16x8 (&KP)[8], bf16x8 (&vf)[8],
    const bf16x8 (&qf0)[4], const bf16x8 (&qf1)[4],
    f32x16 (&oT0)[2], f32x16 (&oT1)[2], float& lsum0, float& lsum1) {
  // V for this iter (used in ~1200 cyc)
#pragma unroll
  for (int dt = 0; dt < 2; dt++)
#pragma unroll
    for (int ks = 0; ks < 4; ks++)
      vf[dt * 4 + ks] =
          *(const bf16x8*)(vlane + dt * (32 * S_LEN) + t * 128 + ks * 16);
  // K for next iter (used in ~2300 cyc)
  if (t < 15) {
#pragma unroll
    for (int kt = 0; kt < 2; kt++)
#pragma unroll
      for (int dk = 0; dk < 4; dk++)
        KP[kt * 4 + dk] =
            *(const bf16x8*)(klane + (t + 1) * 8192 + kt * 2048 + dk * 16);
  }

  // QK^T: each K-fragment feeds both q-halves
  f32x16 st0[2] = {}, st1[2] = {};
  __builtin_amdgcn_s_setprio(1);
#pragma unroll
  for (int kt = 0; kt < 2; kt++)
#pragma unroll
    for (int dk = 0; dk < 4; dk++) {
      st0[kt] = __builtin_amdgcn_mfma_f32_32x32x16_bf16(KU[kt * 4 + dk], qf0[dk],
                                                        st0[kt], 0, 0, 0);
      st1[kt] = __builtin_amdgcn_mfma_f32_32x32x16_bf16(KU[kt * 4 + dk], qf1[dk],
                                                        st1[kt], 0, 0, 0);
    }
  __builtin_amdgcn_s_setprio(0);

  // exp -> pack -> permlane swap -> PV (P never leaves registers)
#pragma unroll
  for (int kt = 0; kt < 2; kt++)
#pragma unroll
    for (int hk = 0; hk < 2; hk++) {
      const int ks = kt * 2 + hk;
      float e0[8], e1[8];
#pragma unroll
      for (int r = 0; r < 8; r++) e0[r] = __expf(st0[kt][hk * 8 + r]);
#pragma unroll
      for (int r = 0; r < 8; r++) e1[r] = __expf(st1[kt][hk * 8 + r]);
      lsum0 += ((e0[0] + e0[1]) + (e0[2] + e0[3])) + ((e0[4] + e0[5]) + (e0[6] + e0[7]));
      lsum1 += ((e1[0] + e1[1]) + (e1[2] + e1[3])) + ((e1[4] + e1[5]) + (e1[6] + e1[7]));
      uint32 p00, p01, p02, p03, p10, p11, p12, p13;
      asm("v_cvt_pk_bf16_f32 %0, %1, %2" : "=v"(p00) : "v"(e0[0]), "v"(e0[1]));
      asm("v_cvt_pk_bf16_f32 %0, %1, %2" : "=v"(p01) : "v"(e0[2]), "v"(e0[3]));
      asm("v_cvt_pk_bf16_f32 %0, %1, %2" : "=v"(p02) : "v"(e0[4]), "v"(e0[5]));
      asm("v_cvt_pk_bf16_f32 %0, %1, %2" : "=v"(p03) : "v"(e0[6]), "v"(e0[7]));
      asm("v_cvt_pk_bf16_f32 %0, %1, %2" : "=v"(p10) : "v"(e1[0]), "v"(e1[1]));
      asm("v_cvt_pk_bf16_f32 %0, %1, %2" : "=v"(p11) : "v"(e1[2]), "v"(e1[3]));
      asm("v_cvt_pk_bf16_f32 %0, %1, %2" : "=v"(p12) : "v"(e1[4]), "v"(e1[5]));
      asm("v_cvt_pk_bf16_f32 %0, %1, %2" : "=v"(p13) : "v"(e1[6]), "v"(e1[7]));
      asm("v_permlane32_swap_b32 %0, %1" : "+v"(p00), "+v"(p02));
      asm("v_permlane32_swap_b32 %0, %1" : "+v"(p01), "+v"(p03));
      asm("v_permlane32_swap_b32 %0, %1" : "+v"(p10), "+v"(p12));
      asm("v_permlane32_swap_b32 %0, %1" : "+v"(p11), "+v"(p13));
      union { uint32 u[4]; bf16x8 v; } pf0, pf1;
      pf0.u[0] = p00; pf0.u[1] = p01; pf0.u[2] = p02; pf0.u[3] = p03;
      pf1.u[0] = p10; pf1.u[1] = p11; pf1.u[2] = p12; pf1.u[3] = p13;
      __builtin_amdgcn_s_setprio(1);
#pragma unroll
      for (int dt = 0; dt < 2; dt++) {
        oT0[dt] = __builtin_amdgcn_mfma_f32_32x32x16_bf16(vf[dt * 4 + ks], pf0.v,
                                                          oT0[dt], 0, 0, 0);
        oT1[dt] = __builtin_amdgcn_mfma_f32_32x32x16_bf16(vf[dt * 4 + ks], pf1.v,
                                                          oT1[dt], 0, 0, 0);
      }
      __builtin_amdgcn_s_setprio(0);
    }
}

__global__ __launch_bounds__(512, 2) void attn_kernel(
    const bf16* __restrict__ Q, const bf16* __restrict__ K,
    const bf16* __restrict__ VT, bf16* __restrict__ AO) {
  __shared__ __align__(16) float msm[256 * 32 + 256];   // merge buffer (33 KB)

  const int tid  = threadIdx.x;
  const int lane = tid & 63;
  const int wave = tid >> 6;
  const int g    = wave >> 2;      // kv-split group (0/1)
  const int qw   = wave & 3;       // q-wave within group
  const int l31  = lane & 31;
  const int hi   = lane >> 5;

  // XCD-bijective remap: 32 consecutive logical blocks (4 heads) per XCD
  const int bid = (blockIdx.x & 7) * 32 + (blockIdx.x >> 3);
  const int qb  = bid & 7;         // 2048/256
  const int bh  = bid >> 3;        // 0..31

  const bf16* qp = Q + ((size_t)bh * S_LEN + qb * 256 + qw * 64 + l31) * DH;
  // per-lane bases (natural layout; fragment values identical to LDS path)
  const bf16* klane = K + (size_t)bh * S_LEN * DH + (size_t)(g * 64 + l31) * DH + hi * 8;
  const bf16* vlane = VT + (size_t)bh * DH * S_LEN + (size_t)l31 * S_LEN + g * 64 + hi * 8;

  // Q B-fragments for both q-halves: col=q=l31, k-rows = dk*16 + hi*8 + j
  bf16x8 qf0[4], qf1[4];
#pragma unroll
  for (int dk = 0; dk < 4; dk++) {
    qf0[dk] = *(const bf16x8*)(qp + dk * 16 + hi * 8);
    qf1[dk] = *(const bf16x8*)(qp + 32 * DH + dk * 16 + hi * 8);
  }

  f32x16 oT0[2] = {}, oT1[2] = {};
  float lsum0 = 0.f, lsum1 = 0.f;

  bf16x8 kA[8], kB[8], vf[8];
  // prologue: K frags for t=0
#pragma unroll
  for (int kt = 0; kt < 2; kt++)
#pragma unroll
    for (int dk = 0; dk < 4; dk++)
      kA[kt * 4 + dk] = *(const bf16x8*)(klane + kt * 2048 + dk * 16);

  for (int tt = 0; tt < 8; tt++) {
    attn_body(klane, vlane, 2 * tt,     kA, kB, vf, qf0, qf1, oT0, oT1, lsum0, lsum1);
    attn_body(klane, vlane, 2 * tt + 1, kB, kA, vf, qf0, qf1, oT0, oT1, lsum0, lsum1);
  }

  // column total: partner lane (lane^32) holds the other 32 key-rows
  lsum0 += __shfl_xor(lsum0, 32);
  lsum1 += __shfl_xor(lsum1, 32);

  // kv-split merge (group 1 -> group 0), two 32KB rounds (q-half 0 then 1)
  float* mO = msm;                      // 256 rows x 128 B
  float* mL = msm + 256 * 32;
  const int mrow = qw * 64 + lane;

  if (g == 1) {
#pragma unroll
    for (int j = 0; j < 8; j++) {
      const int dt = j >> 2, rb = (j & 3) * 4;
      f32x4 c = { oT0[dt][rb], oT0[dt][rb + 1], oT0[dt][rb + 2], oT0[dt][rb + 3] };
      *(f32x4*)((char*)mO + mrow * 128 + ((j ^ (lane & 7)) * 16)) = c;
    }
    mL[mrow] = lsum0;
  }
  __syncthreads();
  if (g == 0) {
#pragma unroll
    for (int j = 0; j < 8; j++) {
      const int dt = j >> 2, rb = (j & 3) * 4;
      const f32x4 c = *(const f32x4*)((char*)mO + mrow * 128 + ((j ^ (lane & 7)) * 16));
#pragma unroll
      for (int rr = 0; rr < 4; rr++) oT0[dt][rb + rr] += c[rr];
    }
    lsum0 += mL[mrow];
  }
  __syncthreads();
  if (g == 1) {
#pragma unroll
    for (int j = 0; j < 8; j++) {
      const int dt = j >> 2, rb = (j & 3) * 4;
      f32x4 c = { oT1[dt][rb], oT1[dt][rb + 1], oT1[dt][rb + 2], oT1[dt][rb + 3] };
      *(f32x4*)((char*)mO + mrow * 128 + ((j ^ (lane & 7)) * 16)) = c;
    }
    mL[mrow] = lsum1;
  }
  __syncthreads();
  if (g == 0) {
#pragma unroll
    for (int j = 0; j < 8; j++) {
      const int dt = j >> 2, rb = (j & 3) * 4;
      const f32x4 c = *(const f32x4*)((char*)mO + mrow * 128 + ((j ^ (lane & 7)) * 16));
#pragma unroll
      for (int rr = 0; rr < 4; rr++) oT1[dt][rb + rr] += c[rr];
    }
    lsum1 += mL[mrow];

    const float inv0 = 1.0f / (lsum0 + 1e-6f);
    const float inv1 = 1.0f / (lsum1 + 1e-6f);
    const int b = bh >> 4, h = bh & 15;
    const int srow = qb * 256 + qw * 64 + l31;   // q-half 0 row
    const size_t base0 = (size_t)(b * S_LEN + srow) * D_MODEL + h * DH;
    const size_t base1 = base0 + (size_t)32 * D_MODEL;
#pragma unroll
    for (int dt = 0; dt < 2; dt++)
#pragma unroll
      for (int rg = 0; rg < 4; rg++) {
        b16x4 o4;
#pragma unroll
        for (int rr = 0; rr < 4; rr++) o4[rr] = (bf16)(oT0[dt][rg * 4 + rr] * inv0);
        *(b16x4*)(AO + base0 + dt * 32 + rg * 8 + hi * 4) = o4;
      }
#pragma unroll
    for (int dt = 0; dt < 2; dt++)
#pragma unroll
      for (int rg = 0; rg < 4; rg++) {
        b16x4 o4;
#pragma unroll
        for (int rr = 0; rr < 4; rr++) o4[rr] = (bf16)(oT1[dt][rg * 4 + rr] * inv1);
        *(b16x4*)(AO + base1 + dt * 32 + rg * 8 + hi * 4) = o4;
      }
  }
}

extern "C" void kernel_launch(void* const* d_in, const int* in_sizes, int n_in,
                              void* d_out, int out_size, void* d_ws, size_t ws_size,
                              hipStream_t stream) {
  const float* x    = (const float*)d_in[0];
  const float* wqkv = (const float*)d_in[1];
  const float* wout = (const float*)d_in[2];
  float* out = (float*)d_out;

  // ws (32 MB): [Q 8MB][K 8MB][VT 8MB][xb 8MB -> AO after gemm_qkv]
  bf16* Q  = (bf16*)d_ws;
  bf16* K  = Q  + (size_t)TOKENS * D_MODEL;
  bf16* VT = K  + (size_t)TOKENS * D_MODEL;
  bf16* xb = VT + (size_t)TOKENS * D_MODEL;
  bf16* AO = xb;                       // xb dead after gemm_qkv
  bf16* wqkvb = (bf16*)d_out;          // d_out dead until gemm_out
  bf16* woutb = Q;                     // Q dead after attn

  convert_kernel<<<dim3(TOKENS * D_MODEL / (256 * 8)), dim3(256), 0, stream>>>(
      x, xb, TOKENS * D_MODEL / 8);
  convert_kernel<<<dim3(3 * D_MODEL * D_MODEL / (256 * 8)), dim3(256), 0, stream>>>(
      wqkv, wqkvb, 3 * D_MODEL * D_MODEL / 8);

  gemm_qkv_kernel<<<dim3(3 * D_MODEL / BN, TOKENS / BM), dim3(256), 0, stream>>>(
      xb, wqkvb, Q, K, VT);

  attn_kernel<<<dim3(BATCH * NH * (S_LEN / 256)), dim3(512), 0, stream>>>(Q, K, VT, AO);

  convert_kernel<<<dim3(D_MODEL * D_MODEL / (256 * 8)), dim3(256), 0, stream>>>(
      wout, woutb, D_MODEL * D_MODEL / 8);

  gemm_out_kernel<<<dim3(D_MODEL / BN, TOKENS / BM), dim3(256), 0, stream>>>(
      AO, woutb, out);
}

// Round 4
// 193.660 us; speedup vs baseline: 1.2344x; 1.2344x over previous
//
#include <hip/hip_runtime.h>
#include <hip/hip_bf16.h>
#include <stdint.h>

#define S_LEN   2048
#define D_MODEL 1024
#define NH      16
#define DH      64
#define BATCH   2
#define TOKENS  (BATCH * S_LEN)   // 4096

typedef __bf16 bf16;
typedef __bf16 bf16x8 __attribute__((ext_vector_type(8)));
typedef __bf16 b16x4  __attribute__((ext_vector_type(4)));
typedef float  f32x4  __attribute__((ext_vector_type(4)));
typedef float  f32x16 __attribute__((ext_vector_type(16)));
typedef unsigned int uint32;

__device__ __forceinline__ void async_lds16(const void* g, void* l) {
  __builtin_amdgcn_global_load_lds((__attribute__((address_space(1))) void*)g,
                                   (__attribute__((address_space(3))) void*)l,
                                   16, 0, 0);
}

// ---------------------------------------------------------------------------
// fp32 -> bf16 bulk convert (8 elems/thread)
// ---------------------------------------------------------------------------
__global__ __launch_bounds__(256) void convert_kernel(
    const float* __restrict__ src, bf16* __restrict__ dst, int n8) {
  const int i = blockIdx.x * 256 + threadIdx.x;
  if (i >= n8) return;
  const f32x4 a = *(const f32x4*)(src + (size_t)i * 8);
  const f32x4 b = *(const f32x4*)(src + (size_t)i * 8 + 4);
  bf16x8 o;
#pragma unroll
  for (int j = 0; j < 4; j++) { o[j] = (bf16)a[j]; o[j + 4] = (bf16)b[j]; }
  *(bf16x8*)(dst + (size_t)i * 8) = o;
}

// ---------------------------------------------------------------------------
// GEMM core (m97-style): C = A * B^T, bf16, async global->LDS, 128x128, BK=32.
// XCD-chunked block swizzle (T1): bijective remap of the block grid into 8
// per-XCD chunks of (gridDim.y/4 x gridDim.x/2) so each XCD's private L2
// sees a compact A-panel x B-panel working set instead of streaming both.
// Requires gridDim.y%4==0 && gridDim.x%2==0 (qkv: 32x24, out: 32x8).
// ---------------------------------------------------------------------------
#define BM 128
#define BN 128
#define BK 32

#define GEMM_CORE(APTR, BPTR, KDIM)                                              \
  __shared__ __align__(16) bf16 As[BM * BK];                                     \
  __shared__ __align__(16) bf16 Bs[BN * BK];                                     \
  const int tid  = threadIdx.x;                                                  \
  const int wave = tid >> 6, lane = tid & 63;                                    \
  const int quad = lane >> 4, l16 = lane & 15;                                   \
  const int id   = blockIdx.y * gridDim.x + blockIdx.x;                          \
  const int xcd  = id & 7, lin = id >> 3;                                        \
  const int ccols = gridDim.x >> 1, crows = gridDim.y >> 2;                      \
  const int m0 = ((xcd >> 1) * crows + lin / ccols) * BM;                        \
  const int n0 = ((xcd & 1) * ccols + lin % ccols) * BN;                         \
  const int wm = (wave >> 1) * 64, wn = (wave & 1) * 64;                         \
  f32x4 acc[4][4] = {};                                                          \
  const int c0 = tid, c1 = tid + 256;                                            \
  for (int k0 = 0; k0 < (KDIM); k0 += BK) {                                      \
    async_lds16((APTR) + (size_t)(m0 + (c0 >> 2)) * (KDIM) + k0 + (c0 & 3) * 8,  \
                As + c0 * 8);                                                    \
    async_lds16((APTR) + (size_t)(m0 + (c1 >> 2)) * (KDIM) + k0 + (c1 & 3) * 8,  \
                As + c1 * 8);                                                    \
    async_lds16((BPTR) + (size_t)(n0 + (c0 >> 2)) * (KDIM) + k0 + (c0 & 3) * 8,  \
                Bs + c0 * 8);                                                    \
    async_lds16((BPTR) + (size_t)(n0 + (c1 >> 2)) * (KDIM) + k0 + (c1 & 3) * 8,  \
                Bs + c1 * 8);                                                    \
    __syncthreads();                                                             \
    bf16x8 af[4], bfr[4];                                                        \
    _Pragma("unroll") for (int i = 0; i < 4; i++)                                \
        af[i] = *(const bf16x8*)(As + (wm + i * 16 + l16) * BK + quad * 8);      \
    _Pragma("unroll") for (int j = 0; j < 4; j++)                                \
        bfr[j] = *(const bf16x8*)(Bs + (wn + j * 16 + l16) * BK + quad * 8);     \
    _Pragma("unroll") for (int i = 0; i < 4; i++)                                \
      _Pragma("unroll") for (int j = 0; j < 4; j++)                              \
        acc[i][j] = __builtin_amdgcn_mfma_f32_16x16x32_bf16(af[i], bfr[j],       \
                                                            acc[i][j], 0, 0, 0); \
    __syncthreads();                                                             \
  }

// GEMM 1: qkv = xb @ Wqkvb^T -> Q (b,h,s,d, x1/8), K (b,h,s,d), VT (b,h,d,s).
__global__ __launch_bounds__(256) void gemm_qkv_kernel(
    const bf16* __restrict__ X, const bf16* __restrict__ W,
    bf16* __restrict__ Qo, bf16* __restrict__ Ko, bf16* __restrict__ VTo) {
  GEMM_CORE(X, W, D_MODEL)
  const int t = n0 >> 10;  // 0=q 1=k 2=v (uniform per block)
#pragma unroll
  for (int i = 0; i < 4; i++) {
    const int rowb = m0 + wm + i * 16 + quad * 4;   // multiple of 4
    const int b = rowb >> 11, s0 = rowb & 2047;
#pragma unroll
    for (int j = 0; j < 4; j++) {
      const int col = n0 + wn + j * 16 + l16;
      const int h = (col >> 6) & 15, d = col & 63;
      if (t == 2) {
        b16x4 v4;
#pragma unroll
        for (int r = 0; r < 4; r++) v4[r] = (bf16)acc[i][j][r];
        *(b16x4*)(VTo + ((size_t)(b * NH + h) * DH + d) * S_LEN + s0) = v4;
      } else {
#pragma unroll
        for (int r = 0; r < 4; r++) {
          const float v = acc[i][j][r];
          if (t == 0)
            Qo[((size_t)(b * NH + h) * S_LEN + s0 + r) * DH + d] = (bf16)(v * 0.125f);
          else
            Ko[((size_t)(b * NH + h) * S_LEN + s0 + r) * DH + d] = (bf16)v;
        }
      }
    }
  }
}

// GEMM 2: out = AO @ Woutb^T -> d_out fp32
__global__ __launch_bounds__(256) void gemm_out_kernel(
    const bf16* __restrict__ A, const bf16* __restrict__ W,
    float* __restrict__ Out) {
  GEMM_CORE(A, W, D_MODEL)
#pragma unroll
  for (int i = 0; i < 4; i++) {
    const int rowb = m0 + wm + i * 16 + quad * 4;
#pragma unroll
    for (int j = 0; j < 4; j++) {
      const int col = n0 + wn + j * 16 + l16;
#pragma unroll
      for (int r = 0; r < 4; r++)
        Out[(size_t)(rowb + r) * D_MODEL + col] = acc[i][j][r];
    }
  }
}

// ---------------------------------------------------------------------------
// Flash attention v9 = v7 (round-2, 49us, known-good) + two stall fixes:
//  (1) ONE barrier per iter: {vmcnt(0); barrier; STAGE(next); compute}.
//      The top barrier proves (a) every wave's tile-t loads landed (each did
//      vmcnt(0) pre-barrier) and (b) every wave finished reading the buffer
//      STAGE overwrites (those reads were consumed in iter t-1, before the
//      wave could reach this barrier). Removes 16x (lgkmcnt(0)+s_barrier).
//  (2) V-fragment ds_reads hoisted above the softmax: ~500cy of exp/pack
//      VALU covers their ~120cy latency (was exposed inside the PV loop).
// 64 q-rows/wave; 8 waves = 2 kv-groups x 4 q-waves; 256 blocks (1/CU).
// Layouts (mfma_f32_32x32x16_bf16, m74/m101-verified C map):
//   C: col=lane&31, row=(r&3)+8*(r>>2)+4*(lane>>5)
//   A: row=lane&31, k=hi*8+j     B: col=lane&31, k=hi*8+j
// ---------------------------------------------------------------------------
__global__ __launch_bounds__(512, 2) void attn_kernel(
    const bf16* __restrict__ Q, const bf16* __restrict__ K,
    const bf16* __restrict__ VT, bf16* __restrict__ AO) {
  __shared__ __align__(16) bf16 smem[2][2][2 * 64 * 64];  // [kv-grp][buf][K|V] 64KB

  const int tid  = threadIdx.x;
  const int lane = tid & 63;
  const int wave = tid >> 6;
  const int g    = wave >> 2;      // kv-split group (0/1)
  const int qw   = wave & 3;       // q-wave within group
  const int l31  = lane & 31;
  const int hi   = lane >> 5;
  const int sw   = l31 & 7;        // read-side XOR swizzle key

  // XCD-bijective remap: 32 consecutive logical blocks (4 heads) per XCD
  const int bid = (blockIdx.x & 7) * 32 + (blockIdx.x >> 3);
  const int qb  = bid & 7;         // 2048/256
  const int bh  = bid >> 3;        // 0..31

  const bf16* qp = Q  + ((size_t)bh * S_LEN + qb * 256 + qw * 64 + l31) * DH;
  const bf16* kp = K  + (size_t)bh * S_LEN * DH;
  const bf16* vp = VT + (size_t)bh * DH * S_LEN;

  // Q B-fragments for both q-halves: col=q=l31, k-rows = dk*16 + hi*8 + j
  bf16x8 qf0[4], qf1[4];
#pragma unroll
  for (int dk = 0; dk < 4; dk++) {
    qf0[dk] = *(const bf16x8*)(qp + dk * 16 + hi * 8);
    qf1[dk] = *(const bf16x8*)(qp + 32 * DH + dk * 16 + hi * 8);
  }

  // staging: 256 threads/group move K(8KB)+V(8KB) as 4x16B chunks/thread.
  // LDS dest linear; global src pre-swizzled so read-side
  // "chunk c of row r lives at c^(r&7)" holds (rule 21).
  const int gtid = tid & 255;
  const int cid0 = gtid, cid1 = gtid + 256;
  const int r0 = cid0 >> 3, c0 = (cid0 & 7) ^ (r0 & 7);
  const int r1 = cid1 >> 3, c1 = (cid1 & 7) ^ (r1 & 7);
  const bf16* ka0 = kp + (size_t)(g * 64 + r0) * DH + c0 * 8;
  const bf16* ka1 = kp + (size_t)(g * 64 + r1) * DH + c1 * 8;
  const bf16* va0 = vp + (size_t)r0 * S_LEN + g * 64 + c0 * 8;
  const bf16* va1 = vp + (size_t)r1 * S_LEN + g * 64 + c1 * 8;
  const int ld0 = cid0 * 8, ld1 = cid1 * 8;   // LDS element offsets

  f32x16 oT0[2] = {}, oT1[2] = {};
  float lsum0 = 0.f, lsum1 = 0.f;

  bf16* sg = &smem[g][0][0];   // group's buf0; buf1 at +8192 elems

#define STAGE(B)                                                                 \
  {                                                                              \
    bf16* s = sg + (B) * (2 * 64 * 64);                                          \
    async_lds16(ka0, s + ld0);                                                   \
    async_lds16(ka1, s + ld1);                                                   \
    async_lds16(va0, s + 4096 + ld0);                                            \
    async_lds16(va1, s + 4096 + ld1);                                            \
    ka0 += 8192; ka1 += 8192; va0 += 128; va1 += 128;                            \
  }

  STAGE(0)

#pragma unroll 2
  for (int t = 0; t < 16; t++) {
    const int cur = t & 1;
    asm volatile("s_waitcnt vmcnt(0)" ::: "memory");   // this wave's tile-t loads landed
    __builtin_amdgcn_s_barrier();                      // all landed; prev-buf reads done
    if (t < 15) {
      STAGE(cur ^ 1)                                   // stage tile t+1 (other buffer)
    }

    const bf16* sb = sg + cur * (2 * 64 * 64);

    // V fragments hoisted: 8x ds_read_b128 in flight across QK + softmax
    bf16x8 vfr[8];
#pragma unroll
    for (int dt = 0; dt < 2; dt++)
#pragma unroll
      for (int ks = 0; ks < 4; ks++)
        vfr[dt * 4 + ks] = *(const bf16x8*)(sb + 4096 + (dt * 32 + l31) * 64 +
                                            (((ks * 2 + hi) ^ sw) * 8));

    // S^T[key][q]: each K-fragment read feeds BOTH q-halves (2 MFMAs/read)
    f32x16 st0[2] = {}, st1[2] = {};
    __builtin_amdgcn_s_setprio(1);
#pragma unroll
    for (int kt = 0; kt < 2; kt++)
#pragma unroll
      for (int dk = 0; dk < 4; dk++) {
        const bf16x8 kf = *(const bf16x8*)(sb + (kt * 32 + l31) * 64 +
                                           (((dk * 2 + hi) ^ sw) * 8));
        st0[kt] = __builtin_amdgcn_mfma_f32_32x32x16_bf16(kf, qf0[dk], st0[kt], 0, 0, 0);
        st1[kt] = __builtin_amdgcn_mfma_f32_32x32x16_bf16(kf, qf1[dk], st1[kt], 0, 0, 0);
      }
    __builtin_amdgcn_s_setprio(0);

    // exp -> pack -> permlane swap -> PV (V already in registers)
#pragma unroll
    for (int kt = 0; kt < 2; kt++)
#pragma unroll
      for (int hk = 0; hk < 2; hk++) {
        const int ks = kt * 2 + hk;
        float e0[8], e1[8];
#pragma unroll
        for (int r = 0; r < 8; r++) e0[r] = __expf(st0[kt][hk * 8 + r]);
#pragma unroll
        for (int r = 0; r < 8; r++) e1[r] = __expf(st1[kt][hk * 8 + r]);
        lsum0 += ((e0[0] + e0[1]) + (e0[2] + e0[3])) + ((e0[4] + e0[5]) + (e0[6] + e0[7]));
        lsum1 += ((e1[0] + e1[1]) + (e1[2] + e1[3])) + ((e1[4] + e1[5]) + (e1[6] + e1[7]));
        uint32 p00, p01, p02, p03, p10, p11, p12, p13;
        asm("v_cvt_pk_bf16_f32 %0, %1, %2" : "=v"(p00) : "v"(e0[0]), "v"(e0[1]));
        asm("v_cvt_pk_bf16_f32 %0, %1, %2" : "=v"(p01) : "v"(e0[2]), "v"(e0[3]));
        asm("v_cvt_pk_bf16_f32 %0, %1, %2" : "=v"(p02) : "v"(e0[4]), "v"(e0[5]));
        asm("v_cvt_pk_bf16_f32 %0, %1, %2" : "=v"(p03) : "v"(e0[6]), "v"(e0[7]));
        asm("v_cvt_pk_bf16_f32 %0, %1, %2" : "=v"(p10) : "v"(e1[0]), "v"(e1[1]));
        asm("v_cvt_pk_bf16_f32 %0, %1, %2" : "=v"(p11) : "v"(e1[2]), "v"(e1[3]));
        asm("v_cvt_pk_bf16_f32 %0, %1, %2" : "=v"(p12) : "v"(e1[4]), "v"(e1[5]));
        asm("v_cvt_pk_bf16_f32 %0, %1, %2" : "=v"(p13) : "v"(e1[6]), "v"(e1[7]));
        asm("v_permlane32_swap_b32 %0, %1" : "+v"(p00), "+v"(p02));
        asm("v_permlane32_swap_b32 %0, %1" : "+v"(p01), "+v"(p03));
        asm("v_permlane32_swap_b32 %0, %1" : "+v"(p10), "+v"(p12));
        asm("v_permlane32_swap_b32 %0, %1" : "+v"(p11), "+v"(p13));
        union { uint32 u[4]; bf16x8 v; } pf0, pf1;
        pf0.u[0] = p00; pf0.u[1] = p01; pf0.u[2] = p02; pf0.u[3] = p03;
        pf1.u[0] = p10; pf1.u[1] = p11; pf1.u[2] = p12; pf1.u[3] = p13;
        __builtin_amdgcn_s_setprio(1);
#pragma unroll
        for (int dt = 0; dt < 2; dt++) {
          oT0[dt] = __builtin_amdgcn_mfma_f32_32x32x16_bf16(vfr[dt * 4 + ks], pf0.v,
                                                            oT0[dt], 0, 0, 0);
          oT1[dt] = __builtin_amdgcn_mfma_f32_32x32x16_bf16(vfr[dt * 4 + ks], pf1.v,
                                                            oT1[dt], 0, 0, 0);
        }
        __builtin_amdgcn_s_setprio(0);
      }
  }
#undef STAGE

  __syncthreads();   // all reads of smem done before merge overlays it

  // column total: partner lane (lane^32) holds the other 32 key-rows
  lsum0 += __shfl_xor(lsum0, 32);
  lsum1 += __shfl_xor(lsum1, 32);

  // kv-split merge (group 1 -> group 0), two 32KB rounds (q-half 0 then 1),
  // chunk-swizzled rows; staging buffers are dead after the loop.
  float* mO = (float*)&smem[0][0][0];            // 32 KB: 256 rows x 128 B
  float* mL = mO + 256 * 32;                     // 1 KB
  const int mrow = qw * 64 + lane;

  if (g == 1) {
#pragma unroll
    for (int j = 0; j < 8; j++) {
      const int dt = j >> 2, rb = (j & 3) * 4;
      f32x4 c = { oT0[dt][rb], oT0[dt][rb + 1], oT0[dt][rb + 2], oT0[dt][rb + 3] };
      *(f32x4*)((char*)mO + mrow * 128 + ((j ^ (lane & 7)) * 16)) = c;
    }
    mL[mrow] = lsum0;
  }
  __syncthreads();
  if (g == 0) {
#pragma unroll
    for (int j = 0; j < 8; j++) {
      const int dt = j >> 2, rb = (j & 3) * 4;
      const f32x4 c = *(const f32x4*)((char*)mO + mrow * 128 + ((j ^ (lane & 7)) * 16));
#pragma unroll
      for (int rr = 0; rr < 4; rr++) oT0[dt][rb + rr] += c[rr];
    }
    lsum0 += mL[mrow];
  }
  __syncthreads();
  if (g == 1) {
#pragma unroll
    for (int j = 0; j < 8; j++) {
      const int dt = j >> 2, rb = (j & 3) * 4;
      f32x4 c = { oT1[dt][rb], oT1[dt][rb + 1], oT1[dt][rb + 2], oT1[dt][rb + 3] };
      *(f32x4*)((char*)mO + mrow * 128 + ((j ^ (lane & 7)) * 16)) = c;
    }
    mL[mrow] = lsum1;
  }
  __syncthreads();
  if (g == 0) {
#pragma unroll
    for (int j = 0; j < 8; j++) {
      const int dt = j >> 2, rb = (j & 3) * 4;
      const f32x4 c = *(const f32x4*)((char*)mO + mrow * 128 + ((j ^ (lane & 7)) * 16));
#pragma unroll
      for (int rr = 0; rr < 4; rr++) oT1[dt][rb + rr] += c[rr];
    }
    lsum1 += mL[mrow];

    const float inv0 = 1.0f / (lsum0 + 1e-6f);
    const float inv1 = 1.0f / (lsum1 + 1e-6f);
    const int b = bh >> 4, h = bh & 15;
    const int srow = qb * 256 + qw * 64 + l31;   // q-half 0 row
    const size_t base0 = (size_t)(b * S_LEN + srow) * D_MODEL + h * DH;
    const size_t base1 = base0 + (size_t)32 * D_MODEL;
#pragma unroll
    for (int dt = 0; dt < 2; dt++)
#pragma unroll
      for (int rg = 0; rg < 4; rg++) {
        b16x4 o4;
#pragma unroll
        for (int rr = 0; rr < 4; rr++) o4[rr] = (bf16)(oT0[dt][rg * 4 + rr] * inv0);
        *(b16x4*)(AO + base0 + dt * 32 + rg * 8 + hi * 4) = o4;
      }
#pragma unroll
    for (int dt = 0; dt < 2; dt++)
#pragma unroll
      for (int rg = 0; rg < 4; rg++) {
        b16x4 o4;
#pragma unroll
        for (int rr = 0; rr < 4; rr++) o4[rr] = (bf16)(oT1[dt][rg * 4 + rr] * inv1);
        *(b16x4*)(AO + base1 + dt * 32 + rg * 8 + hi * 4) = o4;
      }
  }
}

extern "C" void kernel_launch(void* const* d_in, const int* in_sizes, int n_in,
                              void* d_out, int out_size, void* d_ws, size_t ws_size,
                              hipStream_t stream) {
  const float* x    = (const float*)d_in[0];
  const float* wqkv = (const float*)d_in[1];
  const float* wout = (const float*)d_in[2];
  float* out = (float*)d_out;

  // ws (32 MB): [Q 8MB][K 8MB][VT 8MB][xb 8MB -> AO after gemm_qkv]
  bf16* Q  = (bf16*)d_ws;
  bf16* K  = Q  + (size_t)TOKENS * D_MODEL;
  bf16* VT = K  + (size_t)TOKENS * D_MODEL;
  bf16* xb = VT + (size_t)TOKENS * D_MODEL;
  bf16* AO = xb;                       // xb dead after gemm_qkv
  bf16* wqkvb = (bf16*)d_out;          // d_out dead until gemm_out
  bf16* woutb = Q;                     // Q dead after attn

  convert_kernel<<<dim3(TOKENS * D_MODEL / (256 * 8)), dim3(256), 0, stream>>>(
      x, xb, TOKENS * D_MODEL / 8);
  convert_kernel<<<dim3(3 * D_MODEL * D_MODEL / (256 * 8)), dim3(256), 0, stream>>>(
      wqkv, wqkvb, 3 * D_MODEL * D_MODEL / 8);

  gemm_qkv_kernel<<<dim3(3 * D_MODEL / BN, TOKENS / BM), dim3(256), 0, stream>>>(
      xb, wqkvb, Q, K, VT);

  attn_kernel<<<dim3(BATCH * NH * (S_LEN / 256)), dim3(512), 0, stream>>>(Q, K, VT, AO);

  convert_kernel<<<dim3(D_MODEL * D_MODEL / (256 * 8)), dim3(256), 0, stream>>>(
      wout, woutb, D_MODEL * D_MODEL / 8);

  gemm_out_kernel<<<dim3(D_MODEL / BN, TOKENS / BM), dim3(256), 0, stream>>>(
      AO, woutb, out);
}

// Round 5
// 187.417 us; speedup vs baseline: 1.2756x; 1.0333x over previous
//
#include <hip/hip_runtime.h>
#include <hip/hip_bf16.h>
#include <stdint.h>

#define S_LEN   2048
#define D_MODEL 1024
#define NH      16
#define DH      64
#define BATCH   2
#define TOKENS  (BATCH * S_LEN)   // 4096

typedef __bf16 bf16;
typedef __bf16 bf16x8 __attribute__((ext_vector_type(8)));
typedef __bf16 b16x4  __attribute__((ext_vector_type(4)));
typedef float  f32x4  __attribute__((ext_vector_type(4)));
typedef float  f32x16 __attribute__((ext_vector_type(16)));
typedef unsigned int uint32;

__device__ __forceinline__ void async_lds16(const void* g, void* l) {
  __builtin_amdgcn_global_load_lds((__attribute__((address_space(1))) void*)g,
                                   (__attribute__((address_space(3))) void*)l,
                                   16, 0, 0);
}

// ---------------------------------------------------------------------------
// fused fp32 -> bf16 bulk convert: x (n0 items) then Wqkv (n1 items), one
// launch instead of two (8 elems/thread). Wout conversion is fused into
// gemm_out's B-staging (no separate kernel).
// ---------------------------------------------------------------------------
__global__ __launch_bounds__(256) void convert2_kernel(
    const float* __restrict__ s0, bf16* __restrict__ d0, int n0,
    const float* __restrict__ s1, bf16* __restrict__ d1, int n1) {
  int i = blockIdx.x * 256 + threadIdx.x;
  const float* s;
  bf16* d;
  if (i < n0) {
    s = s0 + (size_t)i * 8; d = d0 + (size_t)i * 8;
  } else {
    i -= n0;
    if (i >= n1) return;
    s = s1 + (size_t)i * 8; d = d1 + (size_t)i * 8;
  }
  const f32x4 a = *(const f32x4*)s;
  const f32x4 b = *(const f32x4*)(s + 4);
  bf16x8 o;
#pragma unroll
  for (int j = 0; j < 4; j++) { o[j] = (bf16)a[j]; o[j + 4] = (bf16)b[j]; }
  *(bf16x8*)d = o;
}

// ---------------------------------------------------------------------------
// GEMM core (m97-style): C = A * B^T, bf16, async global->LDS, 128x128, BK=32.
// Plain blockIdx mapping (round-4 XCD chunk swizzle regressed ~8us: 5MB
// chunk working set > 4MB per-XCD L2; reverted).
// ---------------------------------------------------------------------------
#define BM 128
#define BN 128
#define BK 32

#define GEMM_CORE(APTR, BPTR, KDIM)                                              \
  __shared__ __align__(16) bf16 As[BM * BK];                                     \
  __shared__ __align__(16) bf16 Bs[BN * BK];                                     \
  const int tid  = threadIdx.x;                                                  \
  const int wave = tid >> 6, lane = tid & 63;                                    \
  const int quad = lane >> 4, l16 = lane & 15;                                   \
  const int m0 = blockIdx.y * BM;                                                \
  const int n0 = blockIdx.x * BN;                                                \
  const int wm = (wave >> 1) * 64, wn = (wave & 1) * 64;                         \
  f32x4 acc[4][4] = {};                                                          \
  const int c0 = tid, c1 = tid + 256;                                            \
  for (int k0 = 0; k0 < (KDIM); k0 += BK) {                                      \
    async_lds16((APTR) + (size_t)(m0 + (c0 >> 2)) * (KDIM) + k0 + (c0 & 3) * 8,  \
                As + c0 * 8);                                                    \
    async_lds16((APTR) + (size_t)(m0 + (c1 >> 2)) * (KDIM) + k0 + (c1 & 3) * 8,  \
                As + c1 * 8);                                                    \
    async_lds16((BPTR) + (size_t)(n0 + (c0 >> 2)) * (KDIM) + k0 + (c0 & 3) * 8,  \
                Bs + c0 * 8);                                                    \
    async_lds16((BPTR) + (size_t)(n0 + (c1 >> 2)) * (KDIM) + k0 + (c1 & 3) * 8,  \
                Bs + c1 * 8);                                                    \
    __syncthreads();                                                             \
    bf16x8 af[4], bfr[4];                                                        \
    _Pragma("unroll") for (int i = 0; i < 4; i++)                                \
        af[i] = *(const bf16x8*)(As + (wm + i * 16 + l16) * BK + quad * 8);      \
    _Pragma("unroll") for (int j = 0; j < 4; j++)                                \
        bfr[j] = *(const bf16x8*)(Bs + (wn + j * 16 + l16) * BK + quad * 8);     \
    _Pragma("unroll") for (int i = 0; i < 4; i++)                                \
      _Pragma("unroll") for (int j = 0; j < 4; j++)                              \
        acc[i][j] = __builtin_amdgcn_mfma_f32_16x16x32_bf16(af[i], bfr[j],       \
                                                            acc[i][j], 0, 0, 0); \
    __syncthreads();                                                             \
  }

// GEMM 1: qkv = xb @ Wqkvb^T -> Q (b,h,s,d, x1/8), K (b,h,s,d), VT (b,h,d,s).
__global__ __launch_bounds__(256) void gemm_qkv_kernel(
    const bf16* __restrict__ X, const bf16* __restrict__ W,
    bf16* __restrict__ Qo, bf16* __restrict__ Ko, bf16* __restrict__ VTo) {
  GEMM_CORE(X, W, D_MODEL)
  const int t = n0 >> 10;  // 0=q 1=k 2=v (uniform per block)
#pragma unroll
  for (int i = 0; i < 4; i++) {
    const int rowb = m0 + wm + i * 16 + quad * 4;   // multiple of 4
    const int b = rowb >> 11, s0 = rowb & 2047;
#pragma unroll
    for (int j = 0; j < 4; j++) {
      const int col = n0 + wn + j * 16 + l16;
      const int h = (col >> 6) & 15, d = col & 63;
      if (t == 2) {
        b16x4 v4;
#pragma unroll
        for (int r = 0; r < 4; r++) v4[r] = (bf16)acc[i][j][r];
        *(b16x4*)(VTo + ((size_t)(b * NH + h) * DH + d) * S_LEN + s0) = v4;
      } else {
#pragma unroll
        for (int r = 0; r < 4; r++) {
          const float v = acc[i][j][r];
          if (t == 0)
            Qo[((size_t)(b * NH + h) * S_LEN + s0 + r) * DH + d] = (bf16)(v * 0.125f);
          else
            Ko[((size_t)(b * NH + h) * S_LEN + s0 + r) * DH + d] = (bf16)v;
        }
      }
    }
  }
}

// GEMM 2: out = AO @ Wout^T -> d_out fp32. B-operand reg-staged DIRECTLY
// from fp32 Wout (2x f32x4 load -> cvt -> ds_write_b128): fuses the wout
// convert kernel away; same (bf16) cast so results are bit-identical.
__global__ __launch_bounds__(256) void gemm_out_kernel(
    const bf16* __restrict__ A, const float* __restrict__ WF,
    float* __restrict__ Out) {
  __shared__ __align__(16) bf16 As[BM * BK];
  __shared__ __align__(16) bf16 Bs[BN * BK];
  const int tid  = threadIdx.x;
  const int wave = tid >> 6, lane = tid & 63;
  const int quad = lane >> 4, l16 = lane & 15;
  const int m0 = blockIdx.y * BM;
  const int n0 = blockIdx.x * BN;
  const int wm = (wave >> 1) * 64, wn = (wave & 1) * 64;
  f32x4 acc[4][4] = {};
  const int c0 = tid, c1 = tid + 256;
  for (int k0 = 0; k0 < D_MODEL; k0 += BK) {
    async_lds16(A + (size_t)(m0 + (c0 >> 2)) * D_MODEL + k0 + (c0 & 3) * 8,
                As + c0 * 8);
    async_lds16(A + (size_t)(m0 + (c1 >> 2)) * D_MODEL + k0 + (c1 & 3) * 8,
                As + c1 * 8);
    {
      const float* wp0 = WF + (size_t)(n0 + (c0 >> 2)) * D_MODEL + k0 + (c0 & 3) * 8;
      const float* wp1 = WF + (size_t)(n0 + (c1 >> 2)) * D_MODEL + k0 + (c1 & 3) * 8;
      const f32x4 a0 = *(const f32x4*)wp0, b0 = *(const f32x4*)(wp0 + 4);
      const f32x4 a1 = *(const f32x4*)wp1, b1 = *(const f32x4*)(wp1 + 4);
      bf16x8 v0, v1;
#pragma unroll
      for (int j = 0; j < 4; j++) {
        v0[j] = (bf16)a0[j]; v0[j + 4] = (bf16)b0[j];
        v1[j] = (bf16)a1[j]; v1[j + 4] = (bf16)b1[j];
      }
      *(bf16x8*)(Bs + c0 * 8) = v0;
      *(bf16x8*)(Bs + c1 * 8) = v1;
    }
    __syncthreads();
    bf16x8 af[4], bfr[4];
#pragma unroll
    for (int i = 0; i < 4; i++)
      af[i] = *(const bf16x8*)(As + (wm + i * 16 + l16) * BK + quad * 8);
#pragma unroll
    for (int j = 0; j < 4; j++)
      bfr[j] = *(const bf16x8*)(Bs + (wn + j * 16 + l16) * BK + quad * 8);
#pragma unroll
    for (int i = 0; i < 4; i++)
#pragma unroll
      for (int j = 0; j < 4; j++)
        acc[i][j] = __builtin_amdgcn_mfma_f32_16x16x32_bf16(af[i], bfr[j],
                                                            acc[i][j], 0, 0, 0);
    __syncthreads();
  }
#pragma unroll
  for (int i = 0; i < 4; i++) {
    const int rowb = m0 + wm + i * 16 + quad * 4;
#pragma unroll
    for (int j = 0; j < 4; j++) {
      const int col = n0 + wn + j * 16 + l16;
#pragma unroll
      for (int r = 0; r < 4; r++)
        Out[(size_t)(rowb + r) * D_MODEL + col] = acc[i][j][r];
    }
  }
}

// ---------------------------------------------------------------------------
// Flash attention v9 (round-4 best, 47.9us): one barrier per iter
// {vmcnt(0); barrier; STAGE(next); compute}; V-fragment ds_reads hoisted
// above the softmax so exp/pack VALU covers their latency.
// 64 q-rows/wave; 8 waves = 2 kv-groups x 4 q-waves; 256 blocks (1/CU).
// Layouts (mfma_f32_32x32x16_bf16, m74/m101-verified C map):
//   C: col=lane&31, row=(r&3)+8*(r>>2)+4*(lane>>5)
//   A: row=lane&31, k=hi*8+j     B: col=lane&31, k=hi*8+j
// ---------------------------------------------------------------------------
__global__ __launch_bounds__(512, 2) void attn_kernel(
    const bf16* __restrict__ Q, const bf16* __restrict__ K,
    const bf16* __restrict__ VT, bf16* __restrict__ AO) {
  __shared__ __align__(16) bf16 smem[2][2][2 * 64 * 64];  // [kv-grp][buf][K|V] 64KB

  const int tid  = threadIdx.x;
  const int lane = tid & 63;
  const int wave = tid >> 6;
  const int g    = wave >> 2;      // kv-split group (0/1)
  const int qw   = wave & 3;       // q-wave within group
  const int l31  = lane & 31;
  const int hi   = lane >> 5;
  const int sw   = l31 & 7;        // read-side XOR swizzle key

  // XCD-bijective remap: 32 consecutive logical blocks (4 heads) per XCD
  const int bid = (blockIdx.x & 7) * 32 + (blockIdx.x >> 3);
  const int qb  = bid & 7;         // 2048/256
  const int bh  = bid >> 3;        // 0..31

  const bf16* qp = Q  + ((size_t)bh * S_LEN + qb * 256 + qw * 64 + l31) * DH;
  const bf16* kp = K  + (size_t)bh * S_LEN * DH;
  const bf16* vp = VT + (size_t)bh * DH * S_LEN;

  // Q B-fragments for both q-halves: col=q=l31, k-rows = dk*16 + hi*8 + j
  bf16x8 qf0[4], qf1[4];
#pragma unroll
  for (int dk = 0; dk < 4; dk++) {
    qf0[dk] = *(const bf16x8*)(qp + dk * 16 + hi * 8);
    qf1[dk] = *(const bf16x8*)(qp + 32 * DH + dk * 16 + hi * 8);
  }

  // staging: 256 threads/group move K(8KB)+V(8KB) as 4x16B chunks/thread.
  // LDS dest linear; global src pre-swizzled so read-side
  // "chunk c of row r lives at c^(r&7)" holds (rule 21).
  const int gtid = tid & 255;
  const int cid0 = gtid, cid1 = gtid + 256;
  const int r0 = cid0 >> 3, c0 = (cid0 & 7) ^ (r0 & 7);
  const int r1 = cid1 >> 3, c1 = (cid1 & 7) ^ (r1 & 7);
  const bf16* ka0 = kp + (size_t)(g * 64 + r0) * DH + c0 * 8;
  const bf16* ka1 = kp + (size_t)(g * 64 + r1) * DH + c1 * 8;
  const bf16* va0 = vp + (size_t)r0 * S_LEN + g * 64 + c0 * 8;
  const bf16* va1 = vp + (size_t)r1 * S_LEN + g * 64 + c1 * 8;
  const int ld0 = cid0 * 8, ld1 = cid1 * 8;   // LDS element offsets

  f32x16 oT0[2] = {}, oT1[2] = {};
  float lsum0 = 0.f, lsum1 = 0.f;

  bf16* sg = &smem[g][0][0];   // group's buf0; buf1 at +8192 elems

#define STAGE(B)                                                                 \
  {                                                                              \
    bf16* s = sg + (B) * (2 * 64 * 64);                                          \
    async_lds16(ka0, s + ld0);                                                   \
    async_lds16(ka1, s + ld1);                                                   \
    async_lds16(va0, s + 4096 + ld0);                                            \
    async_lds16(va1, s + 4096 + ld1);                                            \
    ka0 += 8192; ka1 += 8192; va0 += 128; va1 += 128;                            \
  }

  STAGE(0)

#pragma unroll 2
  for (int t = 0; t < 16; t++) {
    const int cur = t & 1;
    asm volatile("s_waitcnt vmcnt(0)" ::: "memory");   // this wave's tile-t loads landed
    __builtin_amdgcn_s_barrier();                      // all landed; prev-buf reads done
    if (t < 15) {
      STAGE(cur ^ 1)                                   // stage tile t+1 (other buffer)
    }

    const bf16* sb = sg + cur * (2 * 64 * 64);

    // V fragments hoisted: 8x ds_read_b128 in flight across QK + softmax
    bf16x8 vfr[8];
#pragma unroll
    for (int dt = 0; dt < 2; dt++)
#pragma unroll
      for (int ks = 0; ks < 4; ks++)
        vfr[dt * 4 + ks] = *(const bf16x8*)(sb + 4096 + (dt * 32 + l31) * 64 +
                                            (((ks * 2 + hi) ^ sw) * 8));

    // S^T[key][q]: each K-fragment read feeds BOTH q-halves (2 MFMAs/read)
    f32x16 st0[2] = {}, st1[2] = {};
    __builtin_amdgcn_s_setprio(1);
#pragma unroll
    for (int kt = 0; kt < 2; kt++)
#pragma unroll
      for (int dk = 0; dk < 4; dk++) {
        const bf16x8 kf = *(const bf16x8*)(sb + (kt * 32 + l31) * 64 +
                                           (((dk * 2 + hi) ^ sw) * 8));
        st0[kt] = __builtin_amdgcn_mfma_f32_32x32x16_bf16(kf, qf0[dk], st0[kt], 0, 0, 0);
        st1[kt] = __builtin_amdgcn_mfma_f32_32x32x16_bf16(kf, qf1[dk], st1[kt], 0, 0, 0);
      }
    __builtin_amdgcn_s_setprio(0);

    // exp -> pack -> permlane swap -> PV (V already in registers)
#pragma unroll
    for (int kt = 0; kt < 2; kt++)
#pragma unroll
      for (int hk = 0; hk < 2; hk++) {
        const int ks = kt * 2 + hk;
        float e0[8], e1[8];
#pragma unroll
        for (int r = 0; r < 8; r++) e0[r] = __expf(st0[kt][hk * 8 + r]);
#pragma unroll
        for (int r = 0; r < 8; r++) e1[r] = __expf(st1[kt][hk * 8 + r]);
        lsum0 += ((e0[0] + e0[1]) + (e0[2] + e0[3])) + ((e0[4] + e0[5]) + (e0[6] + e0[7]));
        lsum1 += ((e1[0] + e1[1]) + (e1[2] + e1[3])) + ((e1[4] + e1[5]) + (e1[6] + e1[7]));
        uint32 p00, p01, p02, p03, p10, p11, p12, p13;
        asm("v_cvt_pk_bf16_f32 %0, %1, %2" : "=v"(p00) : "v"(e0[0]), "v"(e0[1]));
        asm("v_cvt_pk_bf16_f32 %0, %1, %2" : "=v"(p01) : "v"(e0[2]), "v"(e0[3]));
        asm("v_cvt_pk_bf16_f32 %0, %1, %2" : "=v"(p02) : "v"(e0[4]), "v"(e0[5]));
        asm("v_cvt_pk_bf16_f32 %0, %1, %2" : "=v"(p03) : "v"(e0[6]), "v"(e0[7]));
        asm("v_cvt_pk_bf16_f32 %0, %1, %2" : "=v"(p10) : "v"(e1[0]), "v"(e1[1]));
        asm("v_cvt_pk_bf16_f32 %0, %1, %2" : "=v"(p11) : "v"(e1[2]), "v"(e1[3]));
        asm("v_cvt_pk_bf16_f32 %0, %1, %2" : "=v"(p12) : "v"(e1[4]), "v"(e1[5]));
        asm("v_cvt_pk_bf16_f32 %0, %1, %2" : "=v"(p13) : "v"(e1[6]), "v"(e1[7]));
        asm("v_permlane32_swap_b32 %0, %1" : "+v"(p00), "+v"(p02));
        asm("v_permlane32_swap_b32 %0, %1" : "+v"(p01), "+v"(p03));
        asm("v_permlane32_swap_b32 %0, %1" : "+v"(p10), "+v"(p12));
        asm("v_permlane32_swap_b32 %0, %1" : "+v"(p11), "+v"(p13));
        union { uint32 u[4]; bf16x8 v; } pf0, pf1;
        pf0.u[0] = p00; pf0.u[1] = p01; pf0.u[2] = p02; pf0.u[3] = p03;
        pf1.u[0] = p10; pf1.u[1] = p11; pf1.u[2] = p12; pf1.u[3] = p13;
        __builtin_amdgcn_s_setprio(1);
#pragma unroll
        for (int dt = 0; dt < 2; dt++) {
          oT0[dt] = __builtin_amdgcn_mfma_f32_32x32x16_bf16(vfr[dt * 4 + ks], pf0.v,
                                                            oT0[dt], 0, 0, 0);
          oT1[dt] = __builtin_amdgcn_mfma_f32_32x32x16_bf16(vfr[dt * 4 + ks], pf1.v,
                                                            oT1[dt], 0, 0, 0);
        }
        __builtin_amdgcn_s_setprio(0);
      }
  }
#undef STAGE

  __syncthreads();   // all reads of smem done before merge overlays it

  // column total: partner lane (lane^32) holds the other 32 key-rows
  lsum0 += __shfl_xor(lsum0, 32);
  lsum1 += __shfl_xor(lsum1, 32);

  // kv-split merge (group 1 -> group 0), two 32KB rounds (q-half 0 then 1),
  // chunk-swizzled rows; staging buffers are dead after the loop.
  float* mO = (float*)&smem[0][0][0];            // 32 KB: 256 rows x 128 B
  float* mL = mO + 256 * 32;                     // 1 KB
  const int mrow = qw * 64 + lane;

  if (g == 1) {
#pragma unroll
    for (int j = 0; j < 8; j++) {
      const int dt = j >> 2, rb = (j & 3) * 4;
      f32x4 c = { oT0[dt][rb], oT0[dt][rb + 1], oT0[dt][rb + 2], oT0[dt][rb + 3] };
      *(f32x4*)((char*)mO + mrow * 128 + ((j ^ (lane & 7)) * 16)) = c;
    }
    mL[mrow] = lsum0;
  }
  __syncthreads();
  if (g == 0) {
#pragma unroll
    for (int j = 0; j < 8; j++) {
      const int dt = j >> 2, rb = (j & 3) * 4;
      const f32x4 c = *(const f32x4*)((char*)mO + mrow * 128 + ((j ^ (lane & 7)) * 16));
#pragma unroll
      for (int rr = 0; rr < 4; rr++) oT0[dt][rb + rr] += c[rr];
    }
    lsum0 += mL[mrow];
  }
  __syncthreads();
  if (g == 1) {
#pragma unroll
    for (int j = 0; j < 8; j++) {
      const int dt = j >> 2, rb = (j & 3) * 4;
      f32x4 c = { oT1[dt][rb], oT1[dt][rb + 1], oT1[dt][rb + 2], oT1[dt][rb + 3] };
      *(f32x4*)((char*)mO + mrow * 128 + ((j ^ (lane & 7)) * 16)) = c;
    }
    mL[mrow] = lsum1;
  }
  __syncthreads();
  if (g == 0) {
#pragma unroll
    for (int j = 0; j < 8; j++) {
      const int dt = j >> 2, rb = (j & 3) * 4;
      const f32x4 c = *(const f32x4*)((char*)mO + mrow * 128 + ((j ^ (lane & 7)) * 16));
#pragma unroll
      for (int rr = 0; rr < 4; rr++) oT1[dt][rb + rr] += c[rr];
    }
    lsum1 += mL[mrow];

    const float inv0 = 1.0f / (lsum0 + 1e-6f);
    const float inv1 = 1.0f / (lsum1 + 1e-6f);
    const int b = bh >> 4, h = bh & 15;
    const int srow = qb * 256 + qw * 64 + l31;   // q-half 0 row
    const size_t base0 = (size_t)(b * S_LEN + srow) * D_MODEL + h * DH;
    const size_t base1 = base0 + (size_t)32 * D_MODEL;
#pragma unroll
    for (int dt = 0; dt < 2; dt++)
#pragma unroll
      for (int rg = 0; rg < 4; rg++) {
        b16x4 o4;
#pragma unroll
        for (int rr = 0; rr < 4; rr++) o4[rr] = (bf16)(oT0[dt][rg * 4 + rr] * inv0);
        *(b16x4*)(AO + base0 + dt * 32 + rg * 8 + hi * 4) = o4;
      }
#pragma unroll
    for (int dt = 0; dt < 2; dt++)
#pragma unroll
      for (int rg = 0; rg < 4; rg++) {
        b16x4 o4;
#pragma unroll
        for (int rr = 0; rr < 4; rr++) o4[rr] = (bf16)(oT1[dt][rg * 4 + rr] * inv1);
        *(b16x4*)(AO + base1 + dt * 32 + rg * 8 + hi * 4) = o4;
      }
  }
}

extern "C" void kernel_launch(void* const* d_in, const int* in_sizes, int n_in,
                              void* d_out, int out_size, void* d_ws, size_t ws_size,
                              hipStream_t stream) {
  const float* x    = (const float*)d_in[0];
  const float* wqkv = (const float*)d_in[1];
  const float* wout = (const float*)d_in[2];
  float* out = (float*)d_out;

  // ws (32 MB): [Q 8MB][K 8MB][VT 8MB][xb 8MB -> AO after gemm_qkv]
  bf16* Q  = (bf16*)d_ws;
  bf16* K  = Q  + (size_t)TOKENS * D_MODEL;
  bf16* VT = K  + (size_t)TOKENS * D_MODEL;
  bf16* xb = VT + (size_t)TOKENS * D_MODEL;
  bf16* AO = xb;                       // xb dead after gemm_qkv
  bf16* wqkvb = (bf16*)d_out;          // d_out dead until gemm_out

  const int nx = TOKENS * D_MODEL / 8;          // 524288
  const int nw = 3 * D_MODEL * D_MODEL / 8;     // 393216
  convert2_kernel<<<dim3((nx + nw) / 256), dim3(256), 0, stream>>>(
      x, xb, nx, wqkv, wqkvb, nw);

  gemm_qkv_kernel<<<dim3(3 * D_MODEL / BN, TOKENS / BM), dim3(256), 0, stream>>>(
      xb, wqkvb, Q, K, VT);

  attn_kernel<<<dim3(BATCH * NH * (S_LEN / 256)), dim3(512), 0, stream>>>(Q, K, VT, AO);

  gemm_out_kernel<<<dim3(D_MODEL / BN, TOKENS / BM), dim3(256), 0, stream>>>(
      AO, wout, out);
}

// Round 7
// 179.837 us; speedup vs baseline: 1.3293x; 1.0422x over previous
//
#include <hip/hip_runtime.h>
#include <hip/hip_bf16.h>
#include <stdint.h>

#define S_LEN   2048
#define D_MODEL 1024
#define NH      16
#define DH      64
#define BATCH   2
#define TOKENS  (BATCH * S_LEN)   // 4096

typedef __bf16 bf16;
typedef __bf16 bf16x8 __attribute__((ext_vector_type(8)));
typedef __bf16 b16x4  __attribute__((ext_vector_type(4)));
typedef float  f32x4  __attribute__((ext_vector_type(4)));
typedef float  f32x16 __attribute__((ext_vector_type(16)));
typedef unsigned int uint32;

__device__ __forceinline__ void async_lds16(const void* g, void* l) {
  __builtin_amdgcn_global_load_lds((__attribute__((address_space(1))) void*)g,
                                   (__attribute__((address_space(3))) void*)l,
                                   16, 0, 0);
}

// ---------------------------------------------------------------------------
// fused fp32 -> bf16 bulk convert over two ranges (8 elems/thread).
// Launched twice: {x, Wqkv} up front; {Wout, empty} after attn (woutb lives
// in Q's region, which is only dead once attn completes).
// ---------------------------------------------------------------------------
__global__ __launch_bounds__(256) void convert2_kernel(
    const float* __restrict__ s0, bf16* __restrict__ d0, int n0,
    const float* __restrict__ s1, bf16* __restrict__ d1, int n1) {
  int i = blockIdx.x * 256 + threadIdx.x;
  const float* s;
  bf16* d;
  if (i < n0) {
    s = s0 + (size_t)i * 8; d = d0 + (size_t)i * 8;
  } else {
    i -= n0;
    if (i >= n1) return;
    s = s1 + (size_t)i * 8; d = d1 + (size_t)i * 8;
  }
  const f32x4 a = *(const f32x4*)s;
  const f32x4 b = *(const f32x4*)(s + 4);
  bf16x8 o;
#pragma unroll
  for (int j = 0; j < 4; j++) { o[j] = (bf16)a[j]; o[j + 4] = (bf16)b[j]; }
  *(bf16x8*)d = o;
}

// ---------------------------------------------------------------------------
// GEMM core (m97-style): C = A * B^T, bf16, async global->LDS, 128x128, BK=32.
// Plain blockIdx mapping (XCD chunk swizzle measured -8us in round 4).
// ---------------------------------------------------------------------------
#define BM 128
#define BN 128
#define BK 32

#define GEMM_CORE(APTR, BPTR, KDIM)                                              \
  __shared__ __align__(16) bf16 As[BM * BK];                                     \
  __shared__ __align__(16) bf16 Bs[BN * BK];                                     \
  const int tid  = threadIdx.x;                                                  \
  const int wave = tid >> 6, lane = tid & 63;                                    \
  const int quad = lane >> 4, l16 = lane & 15;                                   \
  const int m0 = blockIdx.y * BM;                                                \
  const int n0 = blockIdx.x * BN;                                                \
  const int wm = (wave >> 1) * 64, wn = (wave & 1) * 64;                         \
  f32x4 acc[4][4] = {};                                                          \
  const int c0 = tid, c1 = tid + 256;                                            \
  for (int k0 = 0; k0 < (KDIM); k0 += BK) {                                      \
    async_lds16((APTR) + (size_t)(m0 + (c0 >> 2)) * (KDIM) + k0 + (c0 & 3) * 8,  \
                As + c0 * 8);                                                    \
    async_lds16((APTR) + (size_t)(m0 + (c1 >> 2)) * (KDIM) + k0 + (c1 & 3) * 8,  \
                As + c1 * 8);                                                    \
    async_lds16((BPTR) + (size_t)(n0 + (c0 >> 2)) * (KDIM) + k0 + (c0 & 3) * 8,  \
                Bs + c0 * 8);                                                    \
    async_lds16((BPTR) + (size_t)(n0 + (c1 >> 2)) * (KDIM) + k0 + (c1 & 3) * 8,  \
                Bs + c1 * 8);                                                    \
    __syncthreads();                                                             \
    bf16x8 af[4], bfr[4];                                                        \
    _Pragma("unroll") for (int i = 0; i < 4; i++)                                \
        af[i] = *(const bf16x8*)(As + (wm + i * 16 + l16) * BK + quad * 8);      \
    _Pragma("unroll") for (int j = 0; j < 4; j++)                                \
        bfr[j] = *(const bf16x8*)(Bs + (wn + j * 16 + l16) * BK + quad * 8);     \
    _Pragma("unroll") for (int i = 0; i < 4; i++)                                \
      _Pragma("unroll") for (int j = 0; j < 4; j++)                              \
        acc[i][j] = __builtin_amdgcn_mfma_f32_16x16x32_bf16(af[i], bfr[j],       \
                                                            acc[i][j], 0, 0, 0); \
    __syncthreads();                                                             \
  }

// GEMM 1: qkv = xb @ Wqkvb^T -> Q (b,h,s,d, x1/8), K (b,h,s,d), VT (b,h,d,s).
__global__ __launch_bounds__(256) void gemm_qkv_kernel(
    const bf16* __restrict__ X, const bf16* __restrict__ W,
    bf16* __restrict__ Qo, bf16* __restrict__ Ko, bf16* __restrict__ VTo) {
  GEMM_CORE(X, W, D_MODEL)
  const int t = n0 >> 10;  // 0=q 1=k 2=v (uniform per block)
#pragma unroll
  for (int i = 0; i < 4; i++) {
    const int rowb = m0 + wm + i * 16 + quad * 4;   // multiple of 4
    const int b = rowb >> 11, s0 = rowb & 2047;
#pragma unroll
    for (int j = 0; j < 4; j++) {
      const int col = n0 + wn + j * 16 + l16;
      const int h = (col >> 6) & 15, d = col & 63;
      if (t == 2) {
        b16x4 v4;
#pragma unroll
        for (int r = 0; r < 4; r++) v4[r] = (bf16)acc[i][j][r];
        *(b16x4*)(VTo + ((size_t)(b * NH + h) * DH + d) * S_LEN + s0) = v4;
      } else {
#pragma unroll
        for (int r = 0; r < 4; r++) {
          const float v = acc[i][j][r];
          if (t == 0)
            Qo[((size_t)(b * NH + h) * S_LEN + s0 + r) * DH + d] = (bf16)(v * 0.125f);
          else
            Ko[((size_t)(b * NH + h) * S_LEN + s0 + r) * DH + d] = (bf16)v;
        }
      }
    }
  }
}

// ---------------------------------------------------------------------------
// GEMM 2: out = AO @ Woutb^T -> fp32. 64x128 tile so the 4096x1024 output
// gives grid 512 (2 blocks/CU, 8 waves/CU) instead of 128^2's 256 blocks
// (1 block/CU = 1 wave/SIMD: a lockstep loop with zero latency hiding —
// the round-5 occupancy diagnosis). Same m97 sync skeleton; bf16 W operand
// (fp32 reg-staging reverted: measured ~-6us in round 5).
// 4 waves: wm=(wave>>1)*32, wn=(wave&1)*64; per-wave 32x64 = acc[2][4].
// ---------------------------------------------------------------------------
#define BM2 64
#define BN2 128

__global__ __launch_bounds__(256) void gemm_out_kernel(
    const bf16* __restrict__ A, const bf16* __restrict__ W,
    float* __restrict__ Out) {
  __shared__ __align__(16) bf16 As[BM2 * BK];   // 4 KB
  __shared__ __align__(16) bf16 Bs[BN2 * BK];   // 8 KB
  const int tid  = threadIdx.x;
  const int wave = tid >> 6, lane = tid & 63;
  const int quad = lane >> 4, l16 = lane & 15;
  const int m0 = blockIdx.y * BM2;
  const int n0 = blockIdx.x * BN2;
  const int wm = (wave >> 1) * 32, wn = (wave & 1) * 64;
  f32x4 acc[2][4] = {};
  const int c0 = tid, c1 = tid + 256;
  for (int k0 = 0; k0 < D_MODEL; k0 += BK) {
    // A tile: 64 rows x 32 cols = 256 chunks (1/thread)
    async_lds16(A + (size_t)(m0 + (c0 >> 2)) * D_MODEL + k0 + (c0 & 3) * 8,
                As + c0 * 8);
    // B tile: 128 rows x 32 cols = 512 chunks (2/thread)
    async_lds16(W + (size_t)(n0 + (c0 >> 2)) * D_MODEL + k0 + (c0 & 3) * 8,
                Bs + c0 * 8);
    async_lds16(W + (size_t)(n0 + (c1 >> 2)) * D_MODEL + k0 + (c1 & 3) * 8,
                Bs + c1 * 8);
    __syncthreads();
    bf16x8 af[2], bfr[4];
#pragma unroll
    for (int i = 0; i < 2; i++)
      af[i] = *(const bf16x8*)(As + (wm + i * 16 + l16) * BK + quad * 8);
#pragma unroll
    for (int j = 0; j < 4; j++)
      bfr[j] = *(const bf16x8*)(Bs + (wn + j * 16 + l16) * BK + quad * 8);
#pragma unroll
    for (int i = 0; i < 2; i++)
#pragma unroll
      for (int j = 0; j < 4; j++)
        acc[i][j] = __builtin_amdgcn_mfma_f32_16x16x32_bf16(af[i], bfr[j],
                                                            acc[i][j], 0, 0, 0);
    __syncthreads();
  }
#pragma unroll
  for (int i = 0; i < 2; i++) {
    const int rowb = m0 + wm + i * 16 + quad * 4;
#pragma unroll
    for (int j = 0; j < 4; j++) {
      const int col = n0 + wn + j * 16 + l16;
#pragma unroll
      for (int r = 0; r < 4; r++)
        Out[(size_t)(rowb + r) * D_MODEL + col] = acc[i][j][r];
    }
  }
}

// ---------------------------------------------------------------------------
// Flash attention v9 (round-4 best, 47.9us -> 47.2 in round 5): one barrier
// per iter {vmcnt(0); barrier; STAGE(next); compute}; V-fragment ds_reads
// hoisted above the softmax so exp/pack VALU covers their latency.
// 64 q-rows/wave; 8 waves = 2 kv-groups x 4 q-waves; 256 blocks (1/CU).
// Layouts (mfma_f32_32x32x16_bf16, m74/m101-verified C map):
//   C: col=lane&31, row=(r&3)+8*(r>>2)+4*(lane>>5)
//   A: row=lane&31, k=hi*8+j     B: col=lane&31, k=hi*8+j
// ---------------------------------------------------------------------------
__global__ __launch_bounds__(512, 2) void attn_kernel(
    const bf16* __restrict__ Q, const bf16* __restrict__ K,
    const bf16* __restrict__ VT, bf16* __restrict__ AO) {
  __shared__ __align__(16) bf16 smem[2][2][2 * 64 * 64];  // [kv-grp][buf][K|V] 64KB

  const int tid  = threadIdx.x;
  const int lane = tid & 63;
  const int wave = tid >> 6;
  const int g    = wave >> 2;      // kv-split group (0/1)
  const int qw   = wave & 3;       // q-wave within group
  const int l31  = lane & 31;
  const int hi   = lane >> 5;
  const int sw   = l31 & 7;        // read-side XOR swizzle key

  // XCD-bijective remap: 32 consecutive logical blocks (4 heads) per XCD
  const int bid = (blockIdx.x & 7) * 32 + (blockIdx.x >> 3);
  const int qb  = bid & 7;         // 2048/256
  const int bh  = bid >> 3;        // 0..31

  const bf16* qp = Q  + ((size_t)bh * S_LEN + qb * 256 + qw * 64 + l31) * DH;
  const bf16* kp = K  + (size_t)bh * S_LEN * DH;
  const bf16* vp = VT + (size_t)bh * DH * S_LEN;

  // Q B-fragments for both q-halves: col=q=l31, k-rows = dk*16 + hi*8 + j
  bf16x8 qf0[4], qf1[4];
#pragma unroll
  for (int dk = 0; dk < 4; dk++) {
    qf0[dk] = *(const bf16x8*)(qp + dk * 16 + hi * 8);
    qf1[dk] = *(const bf16x8*)(qp + 32 * DH + dk * 16 + hi * 8);
  }

  // staging: 256 threads/group move K(8KB)+V(8KB) as 4x16B chunks/thread.
  // LDS dest linear; global src pre-swizzled so read-side
  // "chunk c of row r lives at c^(r&7)" holds (rule 21).
  const int gtid = tid & 255;
  const int cid0 = gtid, cid1 = gtid + 256;
  const int r0 = cid0 >> 3, c0 = (cid0 & 7) ^ (r0 & 7);
  const int r1 = cid1 >> 3, c1 = (cid1 & 7) ^ (r1 & 7);
  const bf16* ka0 = kp + (size_t)(g * 64 + r0) * DH + c0 * 8;
  const bf16* ka1 = kp + (size_t)(g * 64 + r1) * DH + c1 * 8;
  const bf16* va0 = vp + (size_t)r0 * S_LEN + g * 64 + c0 * 8;
  const bf16* va1 = vp + (size_t)r1 * S_LEN + g * 64 + c1 * 8;
  const int ld0 = cid0 * 8, ld1 = cid1 * 8;   // LDS element offsets

  f32x16 oT0[2] = {}, oT1[2] = {};
  float lsum0 = 0.f, lsum1 = 0.f;

  bf16* sg = &smem[g][0][0];   // group's buf0; buf1 at +8192 elems

#define STAGE(B)                                                                 \
  {                                                                              \
    bf16* s = sg + (B) * (2 * 64 * 64);                                          \
    async_lds16(ka0, s + ld0);                                                   \
    async_lds16(ka1, s + ld1);                                                   \
    async_lds16(va0, s + 4096 + ld0);                                            \
    async_lds16(va1, s + 4096 + ld1);                                            \
    ka0 += 8192; ka1 += 8192; va0 += 128; va1 += 128;                            \
  }

  STAGE(0)

#pragma unroll 2
  for (int t = 0; t < 16; t++) {
    const int cur = t & 1;
    asm volatile("s_waitcnt vmcnt(0)" ::: "memory");   // this wave's tile-t loads landed
    __builtin_amdgcn_s_barrier();                      // all landed; prev-buf reads done
    if (t < 15) {
      STAGE(cur ^ 1)                                   // stage tile t+1 (other buffer)
    }

    const bf16* sb = sg + cur * (2 * 64 * 64);

    // V fragments hoisted: 8x ds_read_b128 in flight across QK + softmax
    bf16x8 vfr[8];
#pragma unroll
    for (int dt = 0; dt < 2; dt++)
#pragma unroll
      for (int ks = 0; ks < 4; ks++)
        vfr[dt * 4 + ks] = *(const bf16x8*)(sb + 4096 + (dt * 32 + l31) * 64 +
                                            (((ks * 2 + hi) ^ sw) * 8));

    // S^T[key][q]: each K-fragment read feeds BOTH q-halves (2 MFMAs/read)
    f32x16 st0[2] = {}, st1[2] = {};
    __builtin_amdgcn_s_setprio(1);
#pragma unroll
    for (int kt = 0; kt < 2; kt++)
#pragma unroll
      for (int dk = 0; dk < 4; dk++) {
        const bf16x8 kf = *(const bf16x8*)(sb + (kt * 32 + l31) * 64 +
                                           (((dk * 2 + hi) ^ sw) * 8));
        st0[kt] = __builtin_amdgcn_mfma_f32_32x32x16_bf16(kf, qf0[dk], st0[kt], 0, 0, 0);
        st1[kt] = __builtin_amdgcn_mfma_f32_32x32x16_bf16(kf, qf1[dk], st1[kt], 0, 0, 0);
      }
    __builtin_amdgcn_s_setprio(0);

    // exp -> pack -> permlane swap -> PV (V already in registers)
#pragma unroll
    for (int kt = 0; kt < 2; kt++)
#pragma unroll
      for (int hk = 0; hk < 2; hk++) {
        const int ks = kt * 2 + hk;
        float e0[8], e1[8];
#pragma unroll
        for (int r = 0; r < 8; r++) e0[r] = __expf(st0[kt][hk * 8 + r]);
#pragma unroll
        for (int r = 0; r < 8; r++) e1[r] = __expf(st1[kt][hk * 8 + r]);
        lsum0 += ((e0[0] + e0[1]) + (e0[2] + e0[3])) + ((e0[4] + e0[5]) + (e0[6] + e0[7]));
        lsum1 += ((e1[0] + e1[1]) + (e1[2] + e1[3])) + ((e1[4] + e1[5]) + (e1[6] + e1[7]));
        uint32 p00, p01, p02, p03, p10, p11, p12, p13;
        asm("v_cvt_pk_bf16_f32 %0, %1, %2" : "=v"(p00) : "v"(e0[0]), "v"(e0[1]));
        asm("v_cvt_pk_bf16_f32 %0, %1, %2" : "=v"(p01) : "v"(e0[2]), "v"(e0[3]));
        asm("v_cvt_pk_bf16_f32 %0, %1, %2" : "=v"(p02) : "v"(e0[4]), "v"(e0[5]));
        asm("v_cvt_pk_bf16_f32 %0, %1, %2" : "=v"(p03) : "v"(e0[6]), "v"(e0[7]));
        asm("v_cvt_pk_bf16_f32 %0, %1, %2" : "=v"(p10) : "v"(e1[0]), "v"(e1[1]));
        asm("v_cvt_pk_bf16_f32 %0, %1, %2" : "=v"(p11) : "v"(e1[2]), "v"(e1[3]));
        asm("v_cvt_pk_bf16_f32 %0, %1, %2" : "=v"(p12) : "v"(e1[4]), "v"(e1[5]));
        asm("v_cvt_pk_bf16_f32 %0, %1, %2" : "=v"(p13) : "v"(e1[6]), "v"(e1[7]));
        asm("v_permlane32_swap_b32 %0, %1" : "+v"(p00), "+v"(p02));
        asm("v_permlane32_swap_b32 %0, %1" : "+v"(p01), "+v"(p03));
        asm("v_permlane32_swap_b32 %0, %1" : "+v"(p10), "+v"(p12));
        asm("v_permlane32_swap_b32 %0, %1" : "+v"(p11), "+v"(p13));
        union { uint32 u[4]; bf16x8 v; } pf0, pf1;
        pf0.u[0] = p00; pf0.u[1] = p01; pf0.u[2] = p02; pf0.u[3] = p03;
        pf1.u[0] = p10; pf1.u[1] = p11; pf1.u[2] = p12; pf1.u[3] = p13;
        __builtin_amdgcn_s_setprio(1);
#pragma unroll
        for (int dt = 0; dt < 2; dt++) {
          oT0[dt] = __builtin_amdgcn_mfma_f32_32x32x16_bf16(vfr[dt * 4 + ks], pf0.v,
                                                            oT0[dt], 0, 0, 0);
          oT1[dt] = __builtin_amdgcn_mfma_f32_32x32x16_bf16(vfr[dt * 4 + ks], pf1.v,
                                                            oT1[dt], 0, 0, 0);
        }
        __builtin_amdgcn_s_setprio(0);
      }
  }
#undef STAGE

  __syncthreads();   // all reads of smem done before merge overlays it

  // column total: partner lane (lane^32) holds the other 32 key-rows
  lsum0 += __shfl_xor(lsum0, 32);
  lsum1 += __shfl_xor(lsum1, 32);

  // kv-split merge (group 1 -> group 0), two 32KB rounds (q-half 0 then 1),
  // chunk-swizzled rows; staging buffers are dead after the loop.
  float* mO = (float*)&smem[0][0][0];            // 32 KB: 256 rows x 128 B
  float* mL = mO + 256 * 32;                     // 1 KB
  const int mrow = qw * 64 + lane;

  if (g == 1) {
#pragma unroll
    for (int j = 0; j < 8; j++) {
      const int dt = j >> 2, rb = (j & 3) * 4;
      f32x4 c = { oT0[dt][rb], oT0[dt][rb + 1], oT0[dt][rb + 2], oT0[dt][rb + 3] };
      *(f32x4*)((char*)mO + mrow * 128 + ((j ^ (lane & 7)) * 16)) = c;
    }
    mL[mrow] = lsum0;
  }
  __syncthreads();
  if (g == 0) {
#pragma unroll
    for (int j = 0; j < 8; j++) {
      const int dt = j >> 2, rb = (j & 3) * 4;
      const f32x4 c = *(const f32x4*)((char*)mO + mrow * 128 + ((j ^ (lane & 7)) * 16));
#pragma unroll
      for (int rr = 0; rr < 4; rr++) oT0[dt][rb + rr] += c[rr];
    }
    lsum0 += mL[mrow];
  }
  __syncthreads();
  if (g == 1) {
#pragma unroll
    for (int j = 0; j < 8; j++) {
      const int dt = j >> 2, rb = (j & 3) * 4;
      f32x4 c = { oT1[dt][rb], oT1[dt][rb + 1], oT1[dt][rb + 2], oT1[dt][rb + 3] };
      *(f32x4*)((char*)mO + mrow * 128 + ((j ^ (lane & 7)) * 16)) = c;
    }
    mL[mrow] = lsum1;
  }
  __syncthreads();
  if (g == 0) {
#pragma unroll
    for (int j = 0; j < 8; j++) {
      const int dt = j >> 2, rb = (j & 3) * 4;
      const f32x4 c = *(const f32x4*)((char*)mO + mrow * 128 + ((j ^ (lane & 7)) * 16));
#pragma unroll
      for (int rr = 0; rr < 4; rr++) oT1[dt][rb + rr] += c[rr];
    }
    lsum1 += mL[mrow];

    const float inv0 = 1.0f / (lsum0 + 1e-6f);
    const float inv1 = 1.0f / (lsum1 + 1e-6f);
    const int b = bh >> 4, h = bh & 15;
    const int srow = qb * 256 + qw * 64 + l31;   // q-half 0 row
    const size_t base0 = (size_t)(b * S_LEN + srow) * D_MODEL + h * DH;
    const size_t base1 = base0 + (size_t)32 * D_MODEL;
#pragma unroll
    for (int dt = 0; dt < 2; dt++)
#pragma unroll
      for (int rg = 0; rg < 4; rg++) {
        b16x4 o4;
#pragma unroll
        for (int rr = 0; rr < 4; rr++) o4[rr] = (bf16)(oT0[dt][rg * 4 + rr] * inv0);
        *(b16x4*)(AO + base0 + dt * 32 + rg * 8 + hi * 4) = o4;
      }
#pragma unroll
    for (int dt = 0; dt < 2; dt++)
#pragma unroll
      for (int rg = 0; rg < 4; rg++) {
        b16x4 o4;
#pragma unroll
        for (int rr = 0; rr < 4; rr++) o4[rr] = (bf16)(oT1[dt][rg * 4 + rr] * inv1);
        *(b16x4*)(AO + base1 + dt * 32 + rg * 8 + hi * 4) = o4;
      }
  }
}

extern "C" void kernel_launch(void* const* d_in, const int* in_sizes, int n_in,
                              void* d_out, int out_size, void* d_ws, size_t ws_size,
                              hipStream_t stream) {
  const float* x    = (const float*)d_in[0];
  const float* wqkv = (const float*)d_in[1];
  const float* wout = (const float*)d_in[2];
  float* out = (float*)d_out;

  // ws (32 MB): [Q 8MB][K 8MB][VT 8MB][xb 8MB -> AO after gemm_qkv]
  bf16* Q  = (bf16*)d_ws;
  bf16* K  = Q  + (size_t)TOKENS * D_MODEL;
  bf16* VT = K  + (size_t)TOKENS * D_MODEL;
  bf16* xb = VT + (size_t)TOKENS * D_MODEL;
  bf16* AO = xb;                       // xb dead after gemm_qkv
  bf16* wqkvb = (bf16*)d_out;          // d_out dead until gemm_out
  bf16* woutb = Q;                     // Q dead after attn

  const int nx = TOKENS * D_MODEL / 8;          // 524288
  const int nw = 3 * D_MODEL * D_MODEL / 8;     // 393216
  const int no = D_MODEL * D_MODEL / 8;         // 131072
  convert2_kernel<<<dim3((nx + nw) / 256), dim3(256), 0, stream>>>(
      x, xb, nx, wqkv, wqkvb, nw);

  gemm_qkv_kernel<<<dim3(3 * D_MODEL / BN, TOKENS / BM), dim3(256), 0, stream>>>(
      xb, wqkvb, Q, K, VT);

  attn_kernel<<<dim3(BATCH * NH * (S_LEN / 256)), dim3(512), 0, stream>>>(Q, K, VT, AO);

  convert2_kernel<<<dim3(no / 256), dim3(256), 0, stream>>>(
      wout, woutb, no, wout, woutb, 0);

  gemm_out_kernel<<<dim3(D_MODEL / BN2, TOKENS / BM2), dim3(256), 0, stream>>>(
      AO, woutb, out);
}

// Round 8
// 177.566 us; speedup vs baseline: 1.3463x; 1.0128x over previous
//
#include <hip/hip_runtime.h>
#include <hip/hip_bf16.h>
#include <stdint.h>

#define S_LEN   2048
#define D_MODEL 1024
#define NH      16
#define DH      64
#define BATCH   2
#define TOKENS  (BATCH * S_LEN)   // 4096

typedef __bf16 bf16;
typedef __bf16 bf16x8 __attribute__((ext_vector_type(8)));
typedef __bf16 b16x4  __attribute__((ext_vector_type(4)));
typedef float  f32x4  __attribute__((ext_vector_type(4)));
typedef float  f32x16 __attribute__((ext_vector_type(16)));
typedef unsigned int uint32;

__device__ __forceinline__ void async_lds16(const void* g, void* l) {
  __builtin_amdgcn_global_load_lds((__attribute__((address_space(1))) void*)g,
                                   (__attribute__((address_space(3))) void*)l,
                                   16, 0, 0);
}

#define MFMA16(a, b, c) __builtin_amdgcn_mfma_f32_16x16x32_bf16((a), (b), (c), 0, 0, 0)

// ---------------------------------------------------------------------------
// fused fp32 -> bf16 bulk convert over two ranges (8 elems/thread).
// ---------------------------------------------------------------------------
__global__ __launch_bounds__(256) void convert2_kernel(
    const float* __restrict__ s0, bf16* __restrict__ d0, int n0,
    const float* __restrict__ s1, bf16* __restrict__ d1, int n1) {
  int i = blockIdx.x * 256 + threadIdx.x;
  const float* s;
  bf16* d;
  if (i < n0) {
    s = s0 + (size_t)i * 8; d = d0 + (size_t)i * 8;
  } else {
    i -= n0;
    if (i >= n1) return;
    s = s1 + (size_t)i * 8; d = d1 + (size_t)i * 8;
  }
  const f32x4 a = *(const f32x4*)s;
  const f32x4 b = *(const f32x4*)(s + 4);
  bf16x8 o;
#pragma unroll
  for (int j = 0; j < 4; j++) { o[j] = (bf16)a[j]; o[j + 4] = (bf16)b[j]; }
  *(bf16x8*)d = o;
}

// ---------------------------------------------------------------------------
// GEMM 1: 8-phase 256x256 (m201 template, T3+T4+T2+T5). qkv = xb @ Wqkvb^T.
// 512 threads = 8 waves (2M x 4N); per-wave C = 128x64 = acc[8][4]; BK=64
// (2 kslots of K=32). LDS 128 KB dynamic: A[2][256][64] + B[2][256][64],
// chunk-XOR swizzled (chunk q of row r at LDS chunk q^(r&7); staged via
// pre-swizzled global source, linear gload_lds dest — rule 21).
// Schedule: 4 phases per K-tile; per phase {ds_read quadrant subtile;
// stage 1 half-tile (2 gload_lds); barrier; setprio(1); 16 MFMA; setprio(0);
// barrier}. Stage-ahead = 6 half-tiles: ph0->B-lo(t+1), ph1->B-hi(t+1),
// ph2->A-lo(t+2) [A-lo(t) consumed in ph0], ph3->A-hi(t+2) [consumed ph2].
// vmcnt(4) once per tile at ph3 (in-order: oldest-4-outstanding = tile t+1
// fully landed); never drained to 0 until the tail (t=14).
// ---------------------------------------------------------------------------
__global__ __launch_bounds__(512, 2) void gemm_qkv_kernel(
    const bf16* __restrict__ X, const bf16* __restrict__ W,
    bf16* __restrict__ Qo, bf16* __restrict__ Ko, bf16* __restrict__ VTo) {
  extern __shared__ __align__(16) bf16 smem[];
  bf16* const Asb = smem;            // [2][16384] elems (64 KB)
  bf16* const Bsb = smem + 32768;    // [2][16384] elems (64 KB)

  const int tid  = threadIdx.x;
  const int wave = tid >> 6, lane = tid & 63;
  const int quad = lane >> 4, l16 = lane & 15;
  const int wm = (wave >> 2) * 128;   // wave_m 0..1
  const int wn = (wave & 3) * 64;     // wave_n 0..3
  const int m0 = blockIdx.y * 256;
  const int n0 = blockIdx.x * 256;

  // staging: thread handles 16B chunks c=tid (rows 0..63) and c+512
  // (rows 64..127, same in-row chunk & swizzle) of one 128x64 half-tile.
  const int rowc  = tid >> 3;
  const int koffc = ((tid & 7) ^ (rowc & 7)) * 8;   // pre-swizzled src offset
  const bf16* pAlo = X + (size_t)(m0 + rowc) * D_MODEL + koffc;
  const bf16* pAhi = X + (size_t)(m0 + 128 + rowc) * D_MODEL + koffc;
  const bf16* pBlo = W + (size_t)(n0 + rowc) * D_MODEL + koffc;
  const bf16* pBhi = W + (size_t)(n0 + 128 + rowc) * D_MODEL + koffc;
  const int ldc = tid * 8;   // LDS elem offset of chunk c; c+512 at +4096

  // read-side swizzle: natural chunk (kslot*4+quad) of row r at chunk ^(r&7);
  // r&7 == l16&7 for every fragment row (wm/wn/i*16 have no low-3 bits).
  const int swr = l16 & 7;
  const int ko0 = ((0 + quad) ^ swr) * 8;   // kslot 0 elem offset
  const int ko1 = ((4 + quad) ^ swr) * 8;   // kslot 1

  f32x4 acc[8][4] = {};
  bf16x8 af[4][2], bfr[4][2];

#define STG(P, LB)                                                        \
  { async_lds16((P), (LB) + ldc);                                         \
    async_lds16((P) + (size_t)64 * D_MODEL, (LB) + ldc + 4096); }

#define BAR()                                                             \
  { asm volatile("" ::: "memory");                                        \
    __builtin_amdgcn_s_barrier();                                         \
    asm volatile("" ::: "memory"); }

  // prologue: tile0 A+B -> buf0, tile1 A -> buf1 (12 loads); tile0 landed.
  STG(pAlo, Asb)                 pAlo += 64;
  STG(pAhi, Asb + 8192)          pAhi += 64;
  STG(pBlo, Bsb)                 pBlo += 64;
  STG(pBhi, Bsb + 8192)          pBhi += 64;
  STG(pAlo, Asb + 16384)         pAlo += 64;
  STG(pAhi, Asb + 16384 + 8192)  pAhi += 64;
  asm volatile("s_waitcnt vmcnt(4)" ::: "memory");
  __builtin_amdgcn_s_barrier();

#pragma unroll 2
  for (int t = 0; t < 16; t++) {
    const int cur = t & 1;
    const bf16* Ac = Asb + cur * 16384;
    const bf16* Bc = Bsb + cur * 16384;
    bf16* An = Asb + cur * 16384;          // A staged 2 ahead -> same buffer
    bf16* Bn = Bsb + (cur ^ 1) * 16384;    // B staged 1 ahead -> other buffer

    // phase 0: read A m0-3 + B n0-1; stage B-lo(t+1); MFMA quad (m0-3,n0-1)
#pragma unroll
    for (int i = 0; i < 4; i++) {
      af[i][0] = *(const bf16x8*)(Ac + (wm + i * 16 + l16) * 64 + ko0);
      af[i][1] = *(const bf16x8*)(Ac + (wm + i * 16 + l16) * 64 + ko1);
    }
#pragma unroll
    for (int j = 0; j < 2; j++) {
      bfr[j][0] = *(const bf16x8*)(Bc + (wn + j * 16 + l16) * 64 + ko0);
      bfr[j][1] = *(const bf16x8*)(Bc + (wn + j * 16 + l16) * 64 + ko1);
    }
    if (t < 15) { STG(pBlo, Bn) pBlo += 64; }
    BAR();
    __builtin_amdgcn_s_setprio(1);
#pragma unroll
    for (int i = 0; i < 4; i++)
#pragma unroll
      for (int j = 0; j < 2; j++) {
        acc[i][j] = MFMA16(af[i][0], bfr[j][0], acc[i][j]);
        acc[i][j] = MFMA16(af[i][1], bfr[j][1], acc[i][j]);
      }
    __builtin_amdgcn_s_setprio(0);
    BAR();

    // phase 1: read B n2-3; stage B-hi(t+1); MFMA quad (m0-3,n2-3)
#pragma unroll
    for (int j = 2; j < 4; j++) {
      bfr[j][0] = *(const bf16x8*)(Bc + (wn + j * 16 + l16) * 64 + ko0);
      bfr[j][1] = *(const bf16x8*)(Bc + (wn + j * 16 + l16) * 64 + ko1);
    }
    if (t < 15) { STG(pBhi, Bn + 8192) pBhi += 64; }
    BAR();
    __builtin_amdgcn_s_setprio(1);
#pragma unroll
    for (int i = 0; i < 4; i++)
#pragma unroll
      for (int j = 2; j < 4; j++) {
        acc[i][j] = MFMA16(af[i][0], bfr[j][0], acc[i][j]);
        acc[i][j] = MFMA16(af[i][1], bfr[j][1], acc[i][j]);
      }
    __builtin_amdgcn_s_setprio(0);
    BAR();

    // phase 2: read A m4-7 (reuse af regs); stage A-lo(t+2); MFMA (m4-7,n0-1)
#pragma unroll
    for (int i = 0; i < 4; i++) {
      af[i][0] = *(const bf16x8*)(Ac + (wm + (i + 4) * 16 + l16) * 64 + ko0);
      af[i][1] = *(const bf16x8*)(Ac + (wm + (i + 4) * 16 + l16) * 64 + ko1);
    }
    if (t < 14) { STG(pAlo, An) pAlo += 64; }
    BAR();
    __builtin_amdgcn_s_setprio(1);
#pragma unroll
    for (int i = 0; i < 4; i++)
#pragma unroll
      for (int j = 0; j < 2; j++) {
        acc[i + 4][j] = MFMA16(af[i][0], bfr[j][0], acc[i + 4][j]);
        acc[i + 4][j] = MFMA16(af[i][1], bfr[j][1], acc[i + 4][j]);
      }
    __builtin_amdgcn_s_setprio(0);
    BAR();

    // phase 3: stage A-hi(t+2); counted vmcnt; MFMA quad (m4-7,n2-3)
    if (t < 14) {
      STG(pAhi, An + 8192) pAhi += 64;
      asm volatile("s_waitcnt vmcnt(4)" ::: "memory");   // tile t+1 landed
    } else if (t == 14) {
      asm volatile("s_waitcnt vmcnt(0)" ::: "memory");   // tail drain
    }
    BAR();
    __builtin_amdgcn_s_setprio(1);
#pragma unroll
    for (int i = 0; i < 4; i++)
#pragma unroll
      for (int j = 2; j < 4; j++) {
        acc[i + 4][j] = MFMA16(af[i][0], bfr[j][0], acc[i + 4][j]);
        acc[i + 4][j] = MFMA16(af[i][1], bfr[j][1], acc[i + 4][j]);
      }
    __builtin_amdgcn_s_setprio(0);
    BAR();
  }
#undef STG
#undef BAR

  // epilogue: Q (b,h,s,d, x1/8), K (b,h,s,d), VT (b,h,d,s)
  const int tq = n0 >> 10;  // 0=q 1=k 2=v (uniform per block; 256 | 1024)
#pragma unroll
  for (int i = 0; i < 8; i++) {
    const int rowb = m0 + wm + i * 16 + quad * 4;   // multiple of 4
    const int b = rowb >> 11, s0r = rowb & 2047;
#pragma unroll
    for (int j = 0; j < 4; j++) {
      const int col = n0 + wn + j * 16 + l16;
      const int h = (col >> 6) & 15, d = col & 63;
      if (tq == 2) {
        b16x4 v4;
#pragma unroll
        for (int r = 0; r < 4; r++) v4[r] = (bf16)acc[i][j][r];
        *(b16x4*)(VTo + ((size_t)(b * NH + h) * DH + d) * S_LEN + s0r) = v4;
      } else {
#pragma unroll
        for (int r = 0; r < 4; r++) {
          const float v = acc[i][j][r];
          if (tq == 0)
            Qo[((size_t)(b * NH + h) * S_LEN + s0r + r) * DH + d] = (bf16)(v * 0.125f);
          else
            Ko[((size_t)(b * NH + h) * S_LEN + s0r + r) * DH + d] = (bf16)v;
        }
      }
    }
  }
}

// ---------------------------------------------------------------------------
// GEMM 2: out = AO @ Woutb^T -> fp32. 64x128 tile, grid 512 (2 blocks/CU)
// — round-7 verified (-7.6us vs 128^2 1 block/CU).
// ---------------------------------------------------------------------------
#define BK  32
#define BM2 64
#define BN2 128

__global__ __launch_bounds__(256) void gemm_out_kernel(
    const bf16* __restrict__ A, const bf16* __restrict__ W,
    float* __restrict__ Out) {
  __shared__ __align__(16) bf16 As[BM2 * BK];   // 4 KB
  __shared__ __align__(16) bf16 Bs[BN2 * BK];   // 8 KB
  const int tid  = threadIdx.x;
  const int wave = tid >> 6, lane = tid & 63;
  const int quad = lane >> 4, l16 = lane & 15;
  const int m0 = blockIdx.y * BM2;
  const int n0 = blockIdx.x * BN2;
  const int wm = (wave >> 1) * 32, wn = (wave & 1) * 64;
  f32x4 acc[2][4] = {};
  const int c0 = tid, c1 = tid + 256;
  for (int k0 = 0; k0 < D_MODEL; k0 += BK) {
    async_lds16(A + (size_t)(m0 + (c0 >> 2)) * D_MODEL + k0 + (c0 & 3) * 8,
                As + c0 * 8);
    async_lds16(W + (size_t)(n0 + (c0 >> 2)) * D_MODEL + k0 + (c0 & 3) * 8,
                Bs + c0 * 8);
    async_lds16(W + (size_t)(n0 + (c1 >> 2)) * D_MODEL + k0 + (c1 & 3) * 8,
                Bs + c1 * 8);
    __syncthreads();
    bf16x8 af[2], bfr[4];
#pragma unroll
    for (int i = 0; i < 2; i++)
      af[i] = *(const bf16x8*)(As + (wm + i * 16 + l16) * BK + quad * 8);
#pragma unroll
    for (int j = 0; j < 4; j++)
      bfr[j] = *(const bf16x8*)(Bs + (wn + j * 16 + l16) * BK + quad * 8);
#pragma unroll
    for (int i = 0; i < 2; i++)
#pragma unroll
      for (int j = 0; j < 4; j++)
        acc[i][j] = MFMA16(af[i], bfr[j], acc[i][j]);
    __syncthreads();
  }
#pragma unroll
  for (int i = 0; i < 2; i++) {
    const int rowb = m0 + wm + i * 16 + quad * 4;
#pragma unroll
    for (int j = 0; j < 4; j++) {
      const int col = n0 + wn + j * 16 + l16;
#pragma unroll
      for (int r = 0; r < 4; r++)
        Out[(size_t)(rowb + r) * D_MODEL + col] = acc[i][j][r];
    }
  }
}

// ---------------------------------------------------------------------------
// Flash attention v9 (frozen since round 4; 47.5us): one barrier per iter
// {vmcnt(0); barrier; STAGE(next); compute}; V-fragment ds_reads hoisted
// above the softmax. 64 q-rows/wave; 8 waves = 2 kv-groups x 4 q-waves;
// 256 blocks (1/CU). mfma_f32_32x32x16_bf16, m74/m101-verified C map.
// ---------------------------------------------------------------------------
__global__ __launch_bounds__(512, 2) void attn_kernel(
    const bf16* __restrict__ Q, const bf16* __restrict__ K,
    const bf16* __restrict__ VT, bf16* __restrict__ AO) {
  __shared__ __align__(16) bf16 smem[2][2][2 * 64 * 64];  // [kv-grp][buf][K|V] 64KB

  const int tid  = threadIdx.x;
  const int lane = tid & 63;
  const int wave = tid >> 6;
  const int g    = wave >> 2;      // kv-split group (0/1)
  const int qw   = wave & 3;       // q-wave within group
  const int l31  = lane & 31;
  const int hi   = lane >> 5;
  const int sw   = l31 & 7;        // read-side XOR swizzle key

  const int bid = (blockIdx.x & 7) * 32 + (blockIdx.x >> 3);
  const int qb  = bid & 7;         // 2048/256
  const int bh  = bid >> 3;        // 0..31

  const bf16* qp = Q  + ((size_t)bh * S_LEN + qb * 256 + qw * 64 + l31) * DH;
  const bf16* kp = K  + (size_t)bh * S_LEN * DH;
  const bf16* vp = VT + (size_t)bh * DH * S_LEN;

  bf16x8 qf0[4], qf1[4];
#pragma unroll
  for (int dk = 0; dk < 4; dk++) {
    qf0[dk] = *(const bf16x8*)(qp + dk * 16 + hi * 8);
    qf1[dk] = *(const bf16x8*)(qp + 32 * DH + dk * 16 + hi * 8);
  }

  const int gtid = tid & 255;
  const int cid0 = gtid, cid1 = gtid + 256;
  const int r0 = cid0 >> 3, c0 = (cid0 & 7) ^ (r0 & 7);
  const int r1 = cid1 >> 3, c1 = (cid1 & 7) ^ (r1 & 7);
  const bf16* ka0 = kp + (size_t)(g * 64 + r0) * DH + c0 * 8;
  const bf16* ka1 = kp + (size_t)(g * 64 + r1) * DH + c1 * 8;
  const bf16* va0 = vp + (size_t)r0 * S_LEN + g * 64 + c0 * 8;
  const bf16* va1 = vp + (size_t)r1 * S_LEN + g * 64 + c1 * 8;
  const int ld0 = cid0 * 8, ld1 = cid1 * 8;

  f32x16 oT0[2] = {}, oT1[2] = {};
  float lsum0 = 0.f, lsum1 = 0.f;

  bf16* sg = &smem[g][0][0];

#define STAGE(B)                                                                 \
  {                                                                              \
    bf16* s = sg + (B) * (2 * 64 * 64);                                          \
    async_lds16(ka0, s + ld0);                                                   \
    async_lds16(ka1, s + ld1);                                                   \
    async_lds16(va0, s + 4096 + ld0);                                            \
    async_lds16(va1, s + 4096 + ld1);                                            \
    ka0 += 8192; ka1 += 8192; va0 += 128; va1 += 128;                            \
  }

  STAGE(0)

#pragma unroll 2
  for (int t = 0; t < 16; t++) {
    const int cur = t & 1;
    asm volatile("s_waitcnt vmcnt(0)" ::: "memory");
    __builtin_amdgcn_s_barrier();
    if (t < 15) {
      STAGE(cur ^ 1)
    }

    const bf16* sb = sg + cur * (2 * 64 * 64);

    bf16x8 vfr[8];
#pragma unroll
    for (int dt = 0; dt < 2; dt++)
#pragma unroll
      for (int ks = 0; ks < 4; ks++)
        vfr[dt * 4 + ks] = *(const bf16x8*)(sb + 4096 + (dt * 32 + l31) * 64 +
                                            (((ks * 2 + hi) ^ sw) * 8));

    f32x16 st0[2] = {}, st1[2] = {};
    __builtin_amdgcn_s_setprio(1);
#pragma unroll
    for (int kt = 0; kt < 2; kt++)
#pragma unroll
      for (int dk = 0; dk < 4; dk++) {
        const bf16x8 kf = *(const bf16x8*)(sb + (kt * 32 + l31) * 64 +
                                           (((dk * 2 + hi) ^ sw) * 8));
        st0[kt] = __builtin_amdgcn_mfma_f32_32x32x16_bf16(kf, qf0[dk], st0[kt], 0, 0, 0);
        st1[kt] = __builtin_amdgcn_mfma_f32_32x32x16_bf16(kf, qf1[dk], st1[kt], 0, 0, 0);
      }
    __builtin_amdgcn_s_setprio(0);

#pragma unroll
    for (int kt = 0; kt < 2; kt++)
#pragma unroll
      for (int hk = 0; hk < 2; hk++) {
        const int ks = kt * 2 + hk;
        float e0[8], e1[8];
#pragma unroll
        for (int r = 0; r < 8; r++) e0[r] = __expf(st0[kt][hk * 8 + r]);
#pragma unroll
        for (int r = 0; r < 8; r++) e1[r] = __expf(st1[kt][hk * 8 + r]);
        lsum0 += ((e0[0] + e0[1]) + (e0[2] + e0[3])) + ((e0[4] + e0[5]) + (e0[6] + e0[7]));
        lsum1 += ((e1[0] + e1[1]) + (e1[2] + e1[3])) + ((e1[4] + e1[5]) + (e1[6] + e1[7]));
        uint32 p00, p01, p02, p03, p10, p11, p12, p13;
        asm("v_cvt_pk_bf16_f32 %0, %1, %2" : "=v"(p00) : "v"(e0[0]), "v"(e0[1]));
        asm("v_cvt_pk_bf16_f32 %0, %1, %2" : "=v"(p01) : "v"(e0[2]), "v"(e0[3]));
        asm("v_cvt_pk_bf16_f32 %0, %1, %2" : "=v"(p02) : "v"(e0[4]), "v"(e0[5]));
        asm("v_cvt_pk_bf16_f32 %0, %1, %2" : "=v"(p03) : "v"(e0[6]), "v"(e0[7]));
        asm("v_cvt_pk_bf16_f32 %0, %1, %2" : "=v"(p10) : "v"(e1[0]), "v"(e1[1]));
        asm("v_cvt_pk_bf16_f32 %0, %1, %2" : "=v"(p11) : "v"(e1[2]), "v"(e1[3]));
        asm("v_cvt_pk_bf16_f32 %0, %1, %2" : "=v"(p12) : "v"(e1[4]), "v"(e1[5]));
        asm("v_cvt_pk_bf16_f32 %0, %1, %2" : "=v"(p13) : "v"(e1[6]), "v"(e1[7]));
        asm("v_permlane32_swap_b32 %0, %1" : "+v"(p00), "+v"(p02));
        asm("v_permlane32_swap_b32 %0, %1" : "+v"(p01), "+v"(p03));
        asm("v_permlane32_swap_b32 %0, %1" : "+v"(p10), "+v"(p12));
        asm("v_permlane32_swap_b32 %0, %1" : "+v"(p11), "+v"(p13));
        union { uint32 u[4]; bf16x8 v; } pf0, pf1;
        pf0.u[0] = p00; pf0.u[1] = p01; pf0.u[2] = p02; pf0.u[3] = p03;
        pf1.u[0] = p10; pf1.u[1] = p11; pf1.u[2] = p12; pf1.u[3] = p13;
        __builtin_amdgcn_s_setprio(1);
#pragma unroll
        for (int dt = 0; dt < 2; dt++) {
          oT0[dt] = __builtin_amdgcn_mfma_f32_32x32x16_bf16(vfr[dt * 4 + ks], pf0.v,
                                                            oT0[dt], 0, 0, 0);
          oT1[dt] = __builtin_amdgcn_mfma_f32_32x32x16_bf16(vfr[dt * 4 + ks], pf1.v,
                                                            oT1[dt], 0, 0, 0);
        }
        __builtin_amdgcn_s_setprio(0);
      }
  }
#undef STAGE

  __syncthreads();

  lsum0 += __shfl_xor(lsum0, 32);
  lsum1 += __shfl_xor(lsum1, 32);

  float* mO = (float*)&smem[0][0][0];
  float* mL = mO + 256 * 32;
  const int mrow = qw * 64 + lane;

  if (g == 1) {
#pragma unroll
    for (int j = 0; j < 8; j++) {
      const int dt = j >> 2, rb = (j & 3) * 4;
      f32x4 c = { oT0[dt][rb], oT0[dt][rb + 1], oT0[dt][rb + 2], oT0[dt][rb + 3] };
      *(f32x4*)((char*)mO + mrow * 128 + ((j ^ (lane & 7)) * 16)) = c;
    }
    mL[mrow] = lsum0;
  }
  __syncthreads();
  if (g == 0) {
#pragma unroll
    for (int j = 0; j < 8; j++) {
      const int dt = j >> 2, rb = (j & 3) * 4;
      const f32x4 c = *(const f32x4*)((char*)mO + mrow * 128 + ((j ^ (lane & 7)) * 16));
#pragma unroll
      for (int rr = 0; rr < 4; rr++) oT0[dt][rb + rr] += c[rr];
    }
    lsum0 += mL[mrow];
  }
  __syncthreads();
  if (g == 1) {
#pragma unroll
    for (int j = 0; j < 8; j++) {
      const int dt = j >> 2, rb = (j & 3) * 4;
      f32x4 c = { oT1[dt][rb], oT1[dt][rb + 1], oT1[dt][rb + 2], oT1[dt][rb + 3] };
      *(f32x4*)((char*)mO + mrow * 128 + ((j ^ (lane & 7)) * 16)) = c;
    }
    mL[mrow] = lsum1;
  }
  __syncthreads();
  if (g == 0) {
#pragma unroll
    for (int j = 0; j < 8; j++) {
      const int dt = j >> 2, rb = (j & 3) * 4;
      const f32x4 c = *(const f32x4*)((char*)mO + mrow * 128 + ((j ^ (lane & 7)) * 16));
#pragma unroll
      for (int rr = 0; rr < 4; rr++) oT1[dt][rb + rr] += c[rr];
    }
    lsum1 += mL[mrow];

    const float inv0 = 1.0f / (lsum0 + 1e-6f);
    const float inv1 = 1.0f / (lsum1 + 1e-6f);
    const int b = bh >> 4, h = bh & 15;
    const int srow = qb * 256 + qw * 64 + l31;
    const size_t base0 = (size_t)(b * S_LEN + srow) * D_MODEL + h * DH;
    const size_t base1 = base0 + (size_t)32 * D_MODEL;
#pragma unroll
    for (int dt = 0; dt < 2; dt++)
#pragma unroll
      for (int rg = 0; rg < 4; rg++) {
        b16x4 o4;
#pragma unroll
        for (int rr = 0; rr < 4; rr++) o4[rr] = (bf16)(oT0[dt][rg * 4 + rr] * inv0);
        *(b16x4*)(AO + base0 + dt * 32 + rg * 8 + hi * 4) = o4;
      }
#pragma unroll
    for (int dt = 0; dt < 2; dt++)
#pragma unroll
      for (int rg = 0; rg < 4; rg++) {
        b16x4 o4;
#pragma unroll
        for (int rr = 0; rr < 4; rr++) o4[rr] = (bf16)(oT1[dt][rg * 4 + rr] * inv1);
        *(b16x4*)(AO + base1 + dt * 32 + rg * 8 + hi * 4) = o4;
      }
  }
}

extern "C" void kernel_launch(void* const* d_in, const int* in_sizes, int n_in,
                              void* d_out, int out_size, void* d_ws, size_t ws_size,
                              hipStream_t stream) {
  const float* x    = (const float*)d_in[0];
  const float* wqkv = (const float*)d_in[1];
  const float* wout = (const float*)d_in[2];
  float* out = (float*)d_out;

  // ws (32 MB): [Q 8MB][K 8MB][VT 8MB][xb 8MB -> AO after gemm_qkv]
  bf16* Q  = (bf16*)d_ws;
  bf16* K  = Q  + (size_t)TOKENS * D_MODEL;
  bf16* VT = K  + (size_t)TOKENS * D_MODEL;
  bf16* xb = VT + (size_t)TOKENS * D_MODEL;
  bf16* AO = xb;                       // xb dead after gemm_qkv
  bf16* wqkvb = (bf16*)d_out;          // d_out dead until gemm_out
  bf16* woutb = Q;                     // Q dead after attn

  const int nx = TOKENS * D_MODEL / 8;          // 524288
  const int nw = 3 * D_MODEL * D_MODEL / 8;     // 393216
  const int no = D_MODEL * D_MODEL / 8;         // 131072
  convert2_kernel<<<dim3((nx + nw) / 256), dim3(256), 0, stream>>>(
      x, xb, nx, wqkv, wqkvb, nw);

  gemm_qkv_kernel<<<dim3(3 * D_MODEL / 256, TOKENS / 256), dim3(512),
                    131072, stream>>>(xb, wqkvb, Q, K, VT);

  attn_kernel<<<dim3(BATCH * NH * (S_LEN / 256)), dim3(512), 0, stream>>>(Q, K, VT, AO);

  convert2_kernel<<<dim3(no / 256), dim3(256), 0, stream>>>(
      wout, woutb, no, wout, woutb, 0);

  gemm_out_kernel<<<dim3(D_MODEL / BN2, TOKENS / BM2), dim3(256), 0, stream>>>(
      AO, woutb, out);
}